// Round 9
// baseline (86.739 us; speedup 1.0000x reference)
//
#include <hip/hip_runtime.h>

#define BATCH 8
#define NTOK 16384

typedef __attribute__((ext_vector_type(8))) short bf16x8;
typedef __attribute__((ext_vector_type(4))) short bf16x4;
typedef __attribute__((ext_vector_type(4))) float f32x4;

#define MFMA(a, b, c) __builtin_amdgcn_mfma_f32_16x16x32_bf16(a, b, c, 0, 0, 0)

// proven path: RNE f32->bf16 via bit ops (no inline asm anywhere)
__device__ __forceinline__ short f2bf(float f) {
  unsigned u = __builtin_bit_cast(unsigned, f);
  u = (u + 0x7fffu + ((u >> 16) & 1u)) >> 16;  // RNE
  return (short)u;
}
__device__ __forceinline__ float bf2f(short s) {
  unsigned u = ((unsigned)(unsigned short)s) << 16;
  return __builtin_bit_cast(float, u);
}
__device__ __forceinline__ bf16x8 cvt8(f32x4 v0, f32x4 v1) {
  bf16x8 a;
  a[0] = f2bf(v0[0]); a[1] = f2bf(v0[1]); a[2] = f2bf(v0[2]); a[3] = f2bf(v0[3]);
  a[4] = f2bf(v1[0]); a[5] = f2bf(v1[1]); a[6] = f2bf(v1[2]); a[7] = f2bf(v1[3]);
  return a;
}

// ---------------- prep: conv weight transpose to bf16 (proven) ------------
__global__ void prep_k(const float* __restrict__ w_sr, short* __restrict__ W2T) {
  int i = blockIdx.x * 256 + threadIdx.x;  // grid 1024 -> i < 262144 exactly
  int o = i >> 12, k = i & 4095, t = k >> 6, c = k & 63;
  W2T[i] = f2bf(w_sr[(o << 12) + (c << 6) + t]);
}

// ---------------- conv (8x8 stride-8 patches) as MFMA GEMM (proven) -------
__global__ __launch_bounds__(256) void conv_k(const float* __restrict__ x,
                                              const short* __restrict__ W2T,
                                              float* __restrict__ convP) {
  const int tid = threadIdx.x;
  const int lane = tid & 63;
  const int nt = tid >> 6;
  const int g = lane >> 4;
  const int kq = lane & 15;
  const int pblk = blockIdx.x >> 2;
  const int split = blockIdx.x & 3;
  const int pbase = pblk << 4;
  const int b = pbase >> 8;
  const int p = pbase + kq;
  const int pb = p & 255;
  const int rowbase = ((pb >> 4) << 10) + ((pb & 15) << 3);
  const size_t xb = (size_t)b * NTOK * 64;

  f32x4 acc = (f32x4){0.f, 0.f, 0.f, 0.f};
  const int c0 = split << 5;
#pragma unroll 4
  for (int c32 = c0; c32 < c0 + 32; ++c32) {
    int t = c32 >> 1;
    int hc = (c32 & 1) << 5;
    int token = rowbase + ((t >> 3) << 7) + (t & 7);
    const float* xp = x + xb + ((size_t)token << 6) + hc + (g << 3);
    bf16x8 a = cvt8(*(const f32x4*)xp, *(const f32x4*)(xp + 4));
    bf16x8 wb = *(const bf16x8*)(W2T + ((nt * 16 + kq) << 12) + (c32 << 5) + (g << 3));
    acc = MFMA(a, wb, acc);
  }
#pragma unroll
  for (int r = 0; r < 4; ++r) {
    int prow = pbase + g * 4 + r;
    convP[((split << 11) + prow) * 64 + nt * 16 + kq] = acc[r];
  }
}

// ---------------- bias + LayerNorm + kv projection (proven R2) ------------
__global__ __launch_bounds__(256) void kv_k(const float* __restrict__ convP,
                                            const float* __restrict__ b_sr,
                                            const float* __restrict__ ln_g,
                                            const float* __restrict__ ln_b,
                                            const float* __restrict__ w_kv,
                                            short* __restrict__ Kw,
                                            short* __restrict__ Vtw) {
  __shared__ float wT[64 * 128];
  __shared__ float raw[2][64];
  __shared__ float rowz[2][64];
  const int tid = threadIdx.x;
#pragma unroll 8
  for (int i = 0; i < 32; ++i) {
    int idx = i * 256 + tid;
    int d2 = idx >> 6, c = idx & 63;
    wT[(c << 7) + (d2 ^ (c & 31))] = w_kv[idx];
  }
  const int gr0 = blockIdx.x << 1;
  if (tid < 128) {
    int r = tid >> 6, c = tid & 63;
    int gr = gr0 + r;
    float y = b_sr[c];
#pragma unroll
    for (int s = 0; s < 4; ++s) y += convP[((s << 11) + gr) * 64 + c];
    raw[r][c] = y;
  }
  __syncthreads();
  if (tid < 128) {
    int r = tid >> 6, c = tid & 63;
    float y = raw[r][c];
    float s1 = y, s2 = y * y;
#pragma unroll
    for (int off = 1; off < 64; off <<= 1) {
      s1 += __shfl_xor(s1, off);
      s2 += __shfl_xor(s2, off);
    }
    float mu = s1 * 0.015625f;
    float var = s2 * 0.015625f - mu * mu;
    float rs = rsqrtf(var + 1e-5f);
    rowz[r][c] = (y - mu) * rs * ln_g[c] + ln_b[c];
  }
  __syncthreads();
  {
    int r = tid >> 7, d = tid & 127;
    float acc = 0.f;
#pragma unroll
    for (int c = 0; c < 64; ++c) acc += rowz[r][c] * wT[(c << 7) + (d ^ (c & 31))];
    int gr = gr0 + r;
    int bb = gr >> 8, m = gr & 255;
    if (d < 64)
      Kw[((bb << 8) + m) * 64 + d] = f2bf(acc);
    else
      Vtw[((bb << 6) + (d - 64)) * 256 + m] = f2bf(acc);
  }
}

// ---------------- fold projections into KV --------------------------------
// blocks 0..31:  KQ[b][key][c] = SUM_o Kw[b][key][o] * SCALE*w_q[o][c]
// blocks 32..63: VPT[b][o][key] = SUM_d w_proj[o][d] * Vtw[b][d][key]
__global__ __launch_bounds__(256) void kq_k(const short* __restrict__ Kw,
                                            const short* __restrict__ Vtw,
                                            const float* __restrict__ w_q,
                                            const float* __restrict__ w_proj,
                                            short* __restrict__ KQ,
                                            short* __restrict__ VPT) {
  __shared__ float wl[4096];
  const int t = threadIdx.x;
  const bool isV = blockIdx.x >= 32;
  const float* wsrc = isV ? w_proj : w_q;
  const float scale = isV ? 1.0f : 0.125f;
#pragma unroll
  for (int i = 0; i < 16; ++i) wl[i * 256 + t] = wsrc[i * 256 + t] * scale;
  __syncthreads();

  if (!isV) {
    int b = blockIdx.x >> 2, kg = blockIdx.x & 3;
    int key = kg * 64 + (t >> 2), cc = (t & 3) * 16;
    const short* krow = Kw + (((b << 8) + key) << 6);
    bf16x8 kr[8];
#pragma unroll
    for (int i = 0; i < 8; ++i) kr[i] = *(const bf16x8*)(krow + i * 8);
    float acc[16];
#pragma unroll
    for (int c = 0; c < 16; ++c) acc[c] = 0.f;
#pragma unroll
    for (int o = 0; o < 64; ++o) {
      float kv = bf2f(kr[o >> 3][o & 7]);
#pragma unroll
      for (int c = 0; c < 16; ++c) acc[c] += kv * wl[o * 64 + cc + c];
    }
    short* dst = KQ + (((b << 8) + key) << 6) + cc;
#pragma unroll
    for (int c = 0; c < 16; ++c) dst[c] = f2bf(acc[c]);
  } else {
    int blk = blockIdx.x - 32;
    int b = blk >> 2, og = blk & 3;
    int o = og * 16 + (t >> 4), kc = (t & 15) * 16;
    const short* vt = Vtw + ((size_t)b << 14);
    float acc[16];
#pragma unroll
    for (int j = 0; j < 16; ++j) acc[j] = 0.f;
#pragma unroll
    for (int d = 0; d < 64; ++d) {
      float wv = wl[o * 64 + d];
      const short* vr = vt + d * 256 + kc;
      bf16x8 v0 = *(const bf16x8*)(vr);
      bf16x8 v1 = *(const bf16x8*)(vr + 8);
#pragma unroll
      for (int j = 0; j < 8; ++j) acc[j] += wv * bf2f(v0[j]);
#pragma unroll
      for (int j = 0; j < 8; ++j) acc[8 + j] += wv * bf2f(v1[j]);
    }
    short* dst = VPT + ((size_t)b << 14) + o * 256 + kc;
#pragma unroll
    for (int j = 0; j < 16; ++j) dst[j] = f2bf(acc[j]);
  }
}

// ---------------- attention v4: S^T = KQ*x^T, lane-local E, P*VP ----------
// 512 thr = 8 waves x 32 queries. LDS = KQ 32KB + VPT(padded) 33KB, no scr.
// Swapped QK^T puts each query's S row in ONE lane; PV uses a permuted
// k-order so the E A-fragment is lane-local (zero shuffles, zero LDS).
__global__ __launch_bounds__(512, 4) void attn_k(
    const float* __restrict__ x, const short* __restrict__ KQ,
    const short* __restrict__ VPT, const float* __restrict__ bproj,
    float* __restrict__ out) {
  __shared__ short KQl[256 * 64];   // rows 128B, 16B-slot ^= (row&7)
  __shared__ short VPTl[64 * 264];  // rows padded to 528B, 8B-slot ^= (o&7)

  const int tid = threadIdx.x;
  const int lane = tid & 63;
  const int wid = tid >> 6;
  const int b = blockIdx.x >> 6;
  const int n0 = (blockIdx.x & 63) << 8;
  const int g = lane >> 4;
  const int kq = lane & 15;
  const int tok0 = n0 + wid * 32;
  const size_t xbase = ((size_t)b * NTOK + tok0) * 64;

  // ---- stage KQ and VPT (coalesced reads, swizzled writes) ----
  {
    const uint4* Kg = (const uint4*)(KQ + ((size_t)b << 14));
#pragma unroll
    for (int i = 0; i < 4; ++i) {
      int id = i * 512 + tid;
      int row = id >> 3, s = id & 7;
      *(uint4*)(&KQl[(row << 6) + ((s ^ (row & 7)) << 3)]) = Kg[id];
    }
    const uint4* Vg = (const uint4*)(VPT + ((size_t)b << 14));
#pragma unroll
    for (int i = 0; i < 4; ++i) {
      int id = i * 512 + tid;
      int o = id >> 5, s = id & 31;  // 16B slot within row
      uint4 v = Vg[id];
      int p0 = (2 * s) ^ (o & 7);
      int p1 = (2 * s + 1) ^ (o & 7);
      uint2 lo; lo.x = v.x; lo.y = v.y;
      uint2 hi; hi.x = v.z; hi.y = v.w;
      *(uint2*)(&VPTl[o * 264 + p0 * 4]) = lo;
      *(uint2*)(&VPTl[o * 264 + p1 * 4]) = hi;
    }
  }

  // ---- x loads (independent of staging) ----
  bf16x8 xa[2][2];
#pragma unroll
  for (int m = 0; m < 2; ++m)
#pragma unroll
    for (int kc = 0; kc < 2; ++kc) {
      const float* p = x + xbase + (size_t)(m * 16 + kq) * 64 + kc * 32 + g * 8;
      xa[m][kc] = cvt8(*(const f32x4*)p, *(const f32x4*)(p + 4));
    }
  float bp[4];
#pragma unroll
  for (int nd = 0; nd < 4; ++nd) bp[nd] = bproj[nd * 16 + kq];

  __syncthreads();

  f32x4 pv[2][4];
#pragma unroll
  for (int m = 0; m < 2; ++m)
#pragma unroll
    for (int nd = 0; nd < 4; ++nd) pv[m][nd] = (f32x4){0.f, 0.f, 0.f, 0.f};
  float rsum[2] = {0.f, 0.f};
  f32x4 epair[2][2];  // [m][kt&1]

#pragma unroll
  for (int kt = 0; kt < 16; ++kt) {
    // A = KQ rows (keys kt*16+kq), same fragment pattern as R2's kb (proven)
    int key = kt * 16 + kq;
    bf16x8 kb0 = *(const bf16x8*)(&KQl[(key << 6) + (((0 * 4 + g) ^ (key & 7)) << 3)]);
    bf16x8 kb1 = *(const bf16x8*)(&KQl[(key << 6) + (((1 * 4 + g) ^ (key & 7)) << 3)]);
#pragma unroll
    for (int m = 0; m < 2; ++m) {
      f32x4 s4 = MFMA(kb0, xa[m][0], ((f32x4){0.f, 0.f, 0.f, 0.f}));
      s4 = MFMA(kb1, xa[m][1], s4);
      // lane (g,kq): S^T[key kt*16+g*4+r][query m*16+kq]
      f32x4 e4;
#pragma unroll
      for (int r = 0; r < 4; ++r) e4[r] = __expf(s4[r]);
      rsum[m] += e4[0] + e4[1] + e4[2] + e4[3];
      epair[m][kt & 1] = e4;
    }
    if (kt & 1) {
      int c = kt >> 1;  // 32-key chunk
      // lane-local E A-fragment under permuted k-order pi
      bf16x8 a8[2];
#pragma unroll
      for (int m = 0; m < 2; ++m) {
        a8[m][0] = f2bf(epair[m][0][0]); a8[m][1] = f2bf(epair[m][0][1]);
        a8[m][2] = f2bf(epair[m][0][2]); a8[m][3] = f2bf(epair[m][0][3]);
        a8[m][4] = f2bf(epair[m][1][0]); a8[m][5] = f2bf(epair[m][1][1]);
        a8[m][6] = f2bf(epair[m][1][2]); a8[m][7] = f2bf(epair[m][1][3]);
      }
#pragma unroll
      for (int nd = 0; nd < 4; ++nd) {
        int o = nd * 16 + kq;
        const short* vrow = &VPTl[o * 264];
        int pa = (8 * c + g) ^ (o & 7);
        int pb_ = (8 * c + g + 4) ^ (o & 7);
        bf16x4 lo = *(const bf16x4*)(vrow + pa * 4);
        bf16x4 hi = *(const bf16x4*)(vrow + pb_ * 4);
        bf16x8 vb = (bf16x8){lo[0], lo[1], lo[2], lo[3], hi[0], hi[1], hi[2], hi[3]};
#pragma unroll
        for (int m = 0; m < 2; ++m) pv[m][nd] = MFMA(a8[m], vb, pv[m][nd]);
      }
    }
  }

  // softmax denominator: sum across the 4 g-lanes holding query kq
  float rinv[2];
#pragma unroll
  for (int m = 0; m < 2; ++m) {
    float s = rsum[m];
    s += __shfl_xor(s, 16);
    s += __shfl_xor(s, 32);
    rinv[m] = 1.0f / s;
  }

  // store: D rows = queries m*16+g*4+r, cols o = nd*16+kq
#pragma unroll
  for (int m = 0; m < 2; ++m)
#pragma unroll
    for (int r = 0; r < 4; ++r) {
      float iv = __shfl(rinv[m], g * 4 + r);  // rinv for query g*4+r lives at lane g*4+r
      size_t rowoff = xbase + (size_t)(m * 16 + g * 4 + r) * 64;
#pragma unroll
      for (int nd = 0; nd < 4; ++nd)
        out[rowoff + nd * 16 + kq] = pv[m][nd][r] * iv + bp[nd];
    }
}

extern "C" void kernel_launch(void* const* d_in, const int* in_sizes, int n_in,
                              void* d_out, int out_size, void* d_ws, size_t ws_size,
                              hipStream_t stream) {
  const float* x = (const float*)d_in[0];
  const float* w_q = (const float*)d_in[3];
  const float* w_kv = (const float*)d_in[4];
  const float* w_sr = (const float*)d_in[5];
  const float* b_sr = (const float*)d_in[6];
  const float* ln_g = (const float*)d_in[7];
  const float* ln_b = (const float*)d_in[8];
  const float* w_proj = (const float*)d_in[9];
  const float* b_proj = (const float*)d_in[10];
  float* out = (float*)d_out;

  // workspace layout (3,145,728 B total, < R2-proven 3,162,112):
  // KQ/VPT alias the W2T region — W2T is dead after conv_k (stream-ordered).
  char* ws = (char*)d_ws;
  short* W2T = (short*)(ws);               // 524288 B  [dead after conv_k]
  short* KQ = (short*)(ws);                // 262144 B  [aliases W2T]
  short* VPT = (short*)(ws + 262144);      // 262144 B  [aliases W2T]
  float* convP = (float*)(ws + 524288);    // 2097152 B
  short* Kw = (short*)(ws + 2621440);      // 262144 B
  short* Vtw = (short*)(ws + 2883584);     // 262144 B (end 3145728)

  hipLaunchKernelGGL(prep_k, dim3(1024), dim3(256), 0, stream, w_sr, W2T);
  hipLaunchKernelGGL(conv_k, dim3(512), dim3(256), 0, stream, x, W2T, convP);
  hipLaunchKernelGGL(kv_k, dim3(1024), dim3(256), 0, stream, convP, b_sr, ln_g,
                     ln_b, w_kv, Kw, Vtw);
  hipLaunchKernelGGL(kq_k, dim3(64), dim3(256), 0, stream, Kw, Vtw, w_q, w_proj,
                     KQ, VPT);
  hipLaunchKernelGGL(attn_k, dim3(512), dim3(512), 0, stream, x, KQ, VPT,
                     b_proj, out);
}

// Round 10
// 75.961 us; speedup vs baseline: 1.1419x; 1.1419x over previous
//
#include <hip/hip_runtime.h>

#define BATCH 8
#define NTOK 16384

typedef __attribute__((ext_vector_type(8))) short bf16x8;
typedef __attribute__((ext_vector_type(4))) short bf16x4;
typedef __attribute__((ext_vector_type(4))) float f32x4;

#define MFMA(a, b, c) __builtin_amdgcn_mfma_f32_16x16x32_bf16(a, b, c, 0, 0, 0)

// proven path: RNE f32->bf16 via bit ops (no inline asm anywhere)
__device__ __forceinline__ short f2bf(float f) {
  unsigned u = __builtin_bit_cast(unsigned, f);
  u = (u + 0x7fffu + ((u >> 16) & 1u)) >> 16;  // RNE
  return (short)u;
}
__device__ __forceinline__ float bf2f(short s) {
  unsigned u = ((unsigned)(unsigned short)s) << 16;
  return __builtin_bit_cast(float, u);
}
__device__ __forceinline__ bf16x8 cvt8(f32x4 v0, f32x4 v1) {
  bf16x8 a;
  a[0] = f2bf(v0[0]); a[1] = f2bf(v0[1]); a[2] = f2bf(v0[2]); a[3] = f2bf(v0[3]);
  a[4] = f2bf(v1[0]); a[5] = f2bf(v1[1]); a[6] = f2bf(v1[2]); a[7] = f2bf(v1[3]);
  return a;
}

// ---------------- prep: conv weight transpose to bf16 (proven) ------------
__global__ void prep_k(const float* __restrict__ w_sr, short* __restrict__ W2T) {
  int i = blockIdx.x * 256 + threadIdx.x;  // grid 1024 -> i < 262144 exactly
  int o = i >> 12, k = i & 4095, t = k >> 6, c = k & 63;
  W2T[i] = f2bf(w_sr[(o << 12) + (c << 6) + t]);
}

// ---------------- conv (8x8 stride-8 patches) as MFMA GEMM (proven) -------
__global__ __launch_bounds__(256) void conv_k(const float* __restrict__ x,
                                              const short* __restrict__ W2T,
                                              float* __restrict__ convP) {
  const int tid = threadIdx.x;
  const int lane = tid & 63;
  const int nt = tid >> 6;
  const int g = lane >> 4;
  const int kq = lane & 15;
  const int pblk = blockIdx.x >> 2;
  const int split = blockIdx.x & 3;
  const int pbase = pblk << 4;
  const int b = pbase >> 8;
  const int p = pbase + kq;
  const int pb = p & 255;
  const int rowbase = ((pb >> 4) << 10) + ((pb & 15) << 3);
  const size_t xb = (size_t)b * NTOK * 64;

  f32x4 acc = (f32x4){0.f, 0.f, 0.f, 0.f};
  const int c0 = split << 5;
#pragma unroll 4
  for (int c32 = c0; c32 < c0 + 32; ++c32) {
    int t = c32 >> 1;
    int hc = (c32 & 1) << 5;
    int token = rowbase + ((t >> 3) << 7) + (t & 7);
    const float* xp = x + xb + ((size_t)token << 6) + hc + (g << 3);
    bf16x8 a = cvt8(*(const f32x4*)xp, *(const f32x4*)(xp + 4));
    bf16x8 wb = *(const bf16x8*)(W2T + ((nt * 16 + kq) << 12) + (c32 << 5) + (g << 3));
    acc = MFMA(a, wb, acc);
  }
#pragma unroll
  for (int r = 0; r < 4; ++r) {
    int prow = pbase + g * 4 + r;
    convP[((split << 11) + prow) * 64 + nt * 16 + kq] = acc[r];
  }
}

// ---------------- bias + LayerNorm + kv projection (16 rows/block) --------
// Same per-row math as the proven R2 kernel (bitwise identical); 128 blocks
// instead of 1024 -> w_kv LDS-fill traffic cut 8x.
__global__ __launch_bounds__(256) void kv_k(const float* __restrict__ convP,
                                            const float* __restrict__ b_sr,
                                            const float* __restrict__ ln_g,
                                            const float* __restrict__ ln_b,
                                            const float* __restrict__ w_kv,
                                            short* __restrict__ Kw,
                                            short* __restrict__ Vtw) {
  __shared__ float wT[64 * 128];  // [c][d] swizzled: d ^ (c&31)
  __shared__ float rowz[16][64];
  const int tid = threadIdx.x;
#pragma unroll 8
  for (int i = 0; i < 32; ++i) {
    int idx = i * 256 + tid;
    int d2 = idx >> 6, c = idx & 63;
    wT[(c << 7) + (d2 ^ (c & 31))] = w_kv[idx];
  }
  const int gr0 = blockIdx.x << 4;
  {
    const int c = tid & 63;
    const int w = tid >> 6;  // 4 waves, one row each per pass
#pragma unroll
    for (int pass = 0; pass < 4; ++pass) {
      int row = pass * 4 + w;
      int gr = gr0 + row;
      float y = b_sr[c];
#pragma unroll
      for (int s = 0; s < 4; ++s) y += convP[((s << 11) + gr) * 64 + c];
      float s1 = y, s2 = y * y;
#pragma unroll
      for (int off = 1; off < 64; off <<= 1) {
        s1 += __shfl_xor(s1, off);
        s2 += __shfl_xor(s2, off);
      }
      float mu = s1 * 0.015625f;
      float var = s2 * 0.015625f - mu * mu;
      float rs = rsqrtf(var + 1e-5f);
      rowz[row][c] = (y - mu) * rs * ln_g[c] + ln_b[c];
    }
  }
  __syncthreads();
  {
    const int d = tid & 127;
    const int rg = tid >> 7;  // 2 groups x 8 rows
#pragma unroll
    for (int rr = 0; rr < 8; ++rr) {
      int row = rg * 8 + rr;
      float acc = 0.f;
#pragma unroll
      for (int c = 0; c < 64; ++c) acc += rowz[row][c] * wT[(c << 7) + (d ^ (c & 31))];
      int gr = gr0 + row;
      int bb = gr >> 8, m = gr & 255;
      if (d < 64)
        Kw[((bb << 8) + m) * 64 + d] = f2bf(acc);
      else
        Vtw[((bb << 6) + (d - 64)) * 256 + m] = f2bf(acc);
    }
  }
}

// ---------------- fold projections into KV --------------------------------
// blocks 0..31:  KQ[b][key][c] = SUM_o Kw[b][key][o] * SCALE*w_q[o][c]
// blocks 32..63: VPT[b][o][key] = SUM_d w_proj[o][d] * Vtw[b][d][key]
__global__ __launch_bounds__(256) void kq_k(const short* __restrict__ Kw,
                                            const short* __restrict__ Vtw,
                                            const float* __restrict__ w_q,
                                            const float* __restrict__ w_proj,
                                            short* __restrict__ KQ,
                                            short* __restrict__ VPT) {
  __shared__ float wl[4096];
  const int t = threadIdx.x;
  const bool isV = blockIdx.x >= 32;
  const float* wsrc = isV ? w_proj : w_q;
  const float scale = isV ? 1.0f : 0.125f;
#pragma unroll
  for (int i = 0; i < 16; ++i) wl[i * 256 + t] = wsrc[i * 256 + t] * scale;
  __syncthreads();

  if (!isV) {
    int b = blockIdx.x >> 2, kg = blockIdx.x & 3;
    int key = kg * 64 + (t >> 2), cc = (t & 3) * 16;
    const short* krow = Kw + (((b << 8) + key) << 6);
    bf16x8 kr[8];
#pragma unroll
    for (int i = 0; i < 8; ++i) kr[i] = *(const bf16x8*)(krow + i * 8);
    float acc[16];
#pragma unroll
    for (int c = 0; c < 16; ++c) acc[c] = 0.f;
#pragma unroll
    for (int o = 0; o < 64; ++o) {
      float kv = bf2f(kr[o >> 3][o & 7]);
#pragma unroll
      for (int c = 0; c < 16; ++c) acc[c] += kv * wl[o * 64 + cc + c];
    }
    short* dst = KQ + (((b << 8) + key) << 6) + cc;
#pragma unroll
    for (int c = 0; c < 16; ++c) dst[c] = f2bf(acc[c]);
  } else {
    int blk = blockIdx.x - 32;
    int b = blk >> 2, og = blk & 3;
    int o = og * 16 + (t >> 4), kc = (t & 15) * 16;
    const short* vt = Vtw + ((size_t)b << 14);
    float acc[16];
#pragma unroll
    for (int j = 0; j < 16; ++j) acc[j] = 0.f;
#pragma unroll
    for (int d = 0; d < 64; ++d) {
      float wv = wl[o * 64 + d];
      const short* vr = vt + d * 256 + kc;
      bf16x8 v0 = *(const bf16x8*)(vr);
      bf16x8 v1 = *(const bf16x8*)(vr + 8);
#pragma unroll
      for (int j = 0; j < 8; ++j) acc[j] += wv * bf2f(v0[j]);
#pragma unroll
      for (int j = 0; j < 8; ++j) acc[8 + j] += wv * bf2f(v1[j]);
    }
    short* dst = VPT + ((size_t)b << 14) + o * 256 + kc;
#pragma unroll
    for (int j = 0; j < 16; ++j) dst[j] = f2bf(acc[j]);
  }
}

// ---------------- attention v4: S^T = KQ*x^T, lane-local E, P*VP ----------
// 512 thr = 8 waves x 32 queries. LDS = KQ 32KB + VPT(padded) 33KB, no scr.
// launch_bounds(512,2): 2 blocks/CU (LDS-capped anyway) -> 128-VGPR budget,
// eliminating the scratch spills seen at (512,4)/64 VGPRs in R9.
__global__ __launch_bounds__(512, 2) void attn_k(
    const float* __restrict__ x, const short* __restrict__ KQ,
    const short* __restrict__ VPT, const float* __restrict__ bproj,
    float* __restrict__ out) {
  __shared__ short KQl[256 * 64];   // rows 128B, 16B-slot ^= (row&7)
  __shared__ short VPTl[64 * 264];  // rows padded to 528B, 8B-slot ^= (o&7)

  const int tid = threadIdx.x;
  const int lane = tid & 63;
  const int wid = tid >> 6;
  const int b = blockIdx.x >> 6;
  const int n0 = (blockIdx.x & 63) << 8;
  const int g = lane >> 4;
  const int kq = lane & 15;
  const int tok0 = n0 + wid * 32;
  const size_t xbase = ((size_t)b * NTOK + tok0) * 64;

  // ---- stage KQ and VPT (coalesced reads, swizzled writes) ----
  {
    const uint4* Kg = (const uint4*)(KQ + ((size_t)b << 14));
#pragma unroll
    for (int i = 0; i < 4; ++i) {
      int id = i * 512 + tid;
      int row = id >> 3, s = id & 7;
      *(uint4*)(&KQl[(row << 6) + ((s ^ (row & 7)) << 3)]) = Kg[id];
    }
    const uint4* Vg = (const uint4*)(VPT + ((size_t)b << 14));
#pragma unroll
    for (int i = 0; i < 4; ++i) {
      int id = i * 512 + tid;
      int o = id >> 5, s = id & 31;  // 16B slot within row
      uint4 v = Vg[id];
      int p0 = (2 * s) ^ (o & 7);
      int p1 = (2 * s + 1) ^ (o & 7);
      uint2 lo; lo.x = v.x; lo.y = v.y;
      uint2 hi; hi.x = v.z; hi.y = v.w;
      *(uint2*)(&VPTl[o * 264 + p0 * 4]) = lo;
      *(uint2*)(&VPTl[o * 264 + p1 * 4]) = hi;
    }
  }

  // ---- x loads (independent of staging) ----
  bf16x8 xa[2][2];
#pragma unroll
  for (int m = 0; m < 2; ++m)
#pragma unroll
    for (int kc = 0; kc < 2; ++kc) {
      const float* p = x + xbase + (size_t)(m * 16 + kq) * 64 + kc * 32 + g * 8;
      xa[m][kc] = cvt8(*(const f32x4*)p, *(const f32x4*)(p + 4));
    }
  float bp[4];
#pragma unroll
  for (int nd = 0; nd < 4; ++nd) bp[nd] = bproj[nd * 16 + kq];

  __syncthreads();

  f32x4 pv[2][4];
#pragma unroll
  for (int m = 0; m < 2; ++m)
#pragma unroll
    for (int nd = 0; nd < 4; ++nd) pv[m][nd] = (f32x4){0.f, 0.f, 0.f, 0.f};
  float rsum[2] = {0.f, 0.f};
  f32x4 epair[2][2];  // [m][kt&1]

#pragma unroll
  for (int kt = 0; kt < 16; ++kt) {
    // A = KQ rows (keys kt*16+kq), same fragment pattern as R2's kb (proven)
    int key = kt * 16 + kq;
    bf16x8 kb0 = *(const bf16x8*)(&KQl[(key << 6) + (((0 * 4 + g) ^ (key & 7)) << 3)]);
    bf16x8 kb1 = *(const bf16x8*)(&KQl[(key << 6) + (((1 * 4 + g) ^ (key & 7)) << 3)]);
#pragma unroll
    for (int m = 0; m < 2; ++m) {
      f32x4 s4 = MFMA(kb0, xa[m][0], ((f32x4){0.f, 0.f, 0.f, 0.f}));
      s4 = MFMA(kb1, xa[m][1], s4);
      // lane (g,kq): S^T[key kt*16+g*4+r][query m*16+kq]
      f32x4 e4;
#pragma unroll
      for (int r = 0; r < 4; ++r) e4[r] = __expf(s4[r]);
      rsum[m] += e4[0] + e4[1] + e4[2] + e4[3];
      epair[m][kt & 1] = e4;
    }
    if (kt & 1) {
      int c = kt >> 1;  // 32-key chunk
      // lane-local E A-fragment under permuted k-order pi
      bf16x8 a8[2];
#pragma unroll
      for (int m = 0; m < 2; ++m) {
        a8[m][0] = f2bf(epair[m][0][0]); a8[m][1] = f2bf(epair[m][0][1]);
        a8[m][2] = f2bf(epair[m][0][2]); a8[m][3] = f2bf(epair[m][0][3]);
        a8[m][4] = f2bf(epair[m][1][0]); a8[m][5] = f2bf(epair[m][1][1]);
        a8[m][6] = f2bf(epair[m][1][2]); a8[m][7] = f2bf(epair[m][1][3]);
      }
#pragma unroll
      for (int nd = 0; nd < 4; ++nd) {
        int o = nd * 16 + kq;
        const short* vrow = &VPTl[o * 264];
        int pa = (8 * c + g) ^ (o & 7);
        int pb_ = (8 * c + g + 4) ^ (o & 7);
        bf16x4 lo = *(const bf16x4*)(vrow + pa * 4);
        bf16x4 hi = *(const bf16x4*)(vrow + pb_ * 4);
        bf16x8 vb = (bf16x8){lo[0], lo[1], lo[2], lo[3], hi[0], hi[1], hi[2], hi[3]};
#pragma unroll
        for (int m = 0; m < 2; ++m) pv[m][nd] = MFMA(a8[m], vb, pv[m][nd]);
      }
    }
  }

  // softmax denominator: sum across the 4 g-lanes holding query kq
  float rinv[2];
#pragma unroll
  for (int m = 0; m < 2; ++m) {
    float s = rsum[m];
    s += __shfl_xor(s, 16);
    s += __shfl_xor(s, 32);
    rinv[m] = 1.0f / s;
  }

  // store: D rows = queries m*16+g*4+r, cols o = nd*16+kq
#pragma unroll
  for (int m = 0; m < 2; ++m)
#pragma unroll
    for (int r = 0; r < 4; ++r) {
      float iv = __shfl(rinv[m], g * 4 + r);  // rinv for query g*4+r lives at lane g*4+r
      size_t rowoff = xbase + (size_t)(m * 16 + g * 4 + r) * 64;
#pragma unroll
      for (int nd = 0; nd < 4; ++nd)
        out[rowoff + nd * 16 + kq] = pv[m][nd][r] * iv + bp[nd];
    }
}

extern "C" void kernel_launch(void* const* d_in, const int* in_sizes, int n_in,
                              void* d_out, int out_size, void* d_ws, size_t ws_size,
                              hipStream_t stream) {
  const float* x = (const float*)d_in[0];
  const float* w_q = (const float*)d_in[3];
  const float* w_kv = (const float*)d_in[4];
  const float* w_sr = (const float*)d_in[5];
  const float* b_sr = (const float*)d_in[6];
  const float* ln_g = (const float*)d_in[7];
  const float* ln_b = (const float*)d_in[8];
  const float* w_proj = (const float*)d_in[9];
  const float* b_proj = (const float*)d_in[10];
  float* out = (float*)d_out;

  // workspace layout (3,145,728 B total, < R2-proven 3,162,112):
  // KQ/VPT alias the W2T region — W2T is dead after conv_k (stream-ordered).
  char* ws = (char*)d_ws;
  short* W2T = (short*)(ws);               // 524288 B  [dead after conv_k]
  short* KQ = (short*)(ws);                // 262144 B  [aliases W2T]
  short* VPT = (short*)(ws + 262144);      // 262144 B  [aliases W2T]
  float* convP = (float*)(ws + 524288);    // 2097152 B
  short* Kw = (short*)(ws + 2621440);      // 262144 B
  short* Vtw = (short*)(ws + 2883584);     // 262144 B (end 3145728)

  hipLaunchKernelGGL(prep_k, dim3(1024), dim3(256), 0, stream, w_sr, W2T);
  hipLaunchKernelGGL(conv_k, dim3(512), dim3(256), 0, stream, x, W2T, convP);
  hipLaunchKernelGGL(kv_k, dim3(128), dim3(256), 0, stream, convP, b_sr, ln_g,
                     ln_b, w_kv, Kw, Vtw);
  hipLaunchKernelGGL(kq_k, dim3(64), dim3(256), 0, stream, Kw, Vtw, w_q, w_proj,
                     KQ, VPT);
  hipLaunchKernelGGL(attn_k, dim3(512), dim3(512), 0, stream, x, KQ, VPT,
                     b_proj, out);
}

// Round 11
// 73.692 us; speedup vs baseline: 1.1770x; 1.0308x over previous
//
#include <hip/hip_runtime.h>

#define BATCH 8
#define NTOK 16384

typedef __attribute__((ext_vector_type(8))) short bf16x8;
typedef __attribute__((ext_vector_type(4))) short bf16x4;
typedef __attribute__((ext_vector_type(4))) float f32x4;

#define MFMA(a, b, c) __builtin_amdgcn_mfma_f32_16x16x32_bf16(a, b, c, 0, 0, 0)

// proven path: RNE f32->bf16 via bit ops (no inline asm anywhere)
__device__ __forceinline__ short f2bf(float f) {
  unsigned u = __builtin_bit_cast(unsigned, f);
  u = (u + 0x7fffu + ((u >> 16) & 1u)) >> 16;  // RNE
  return (short)u;
}
__device__ __forceinline__ float bf2f(short s) {
  unsigned u = ((unsigned)(unsigned short)s) << 16;
  return __builtin_bit_cast(float, u);
}
__device__ __forceinline__ bf16x8 cvt8(f32x4 v0, f32x4 v1) {
  bf16x8 a;
  a[0] = f2bf(v0[0]); a[1] = f2bf(v0[1]); a[2] = f2bf(v0[2]); a[3] = f2bf(v0[3]);
  a[4] = f2bf(v1[0]); a[5] = f2bf(v1[1]); a[6] = f2bf(v1[2]); a[7] = f2bf(v1[3]);
  return a;
}

// ---------------- prep: conv weight transpose via padded LDS tile ---------
// W2T[o][t*64+c] = w_sr[o][c][t]; coalesced read AND write, conflict-free.
__global__ __launch_bounds__(256) void prep_k(const float* __restrict__ w_sr,
                                              short* __restrict__ W2T) {
  __shared__ float tile[64 * 65];
  const int o = blockIdx.x;  // 64 blocks
  const float* src = w_sr + (o << 12);
  short* dst = W2T + (o << 12);
  const int tid = threadIdx.x;
#pragma unroll
  for (int k = 0; k < 16; ++k) {
    int idx = k * 256 + tid;        // idx = c*64 + t
    int c = idx >> 6, t = idx & 63;
    tile[c * 65 + t] = src[idx];
  }
  __syncthreads();
#pragma unroll
  for (int k = 0; k < 16; ++k) {
    int idx = k * 256 + tid;        // idx = t*64 + c
    int t = idx >> 6, c = idx & 63;
    dst[idx] = f2bf(tile[c * 65 + t]);
  }
}

// ---------------- conv (8x8 stride-8 patches) as MFMA GEMM, K-split NS ----
template <int NS>
__global__ __launch_bounds__(256) void conv_k(const float* __restrict__ x,
                                              const short* __restrict__ W2T,
                                              float* __restrict__ convP) {
  const int tid = threadIdx.x;
  const int lane = tid & 63;
  const int nt = tid >> 6;
  const int g = lane >> 4;
  const int kq = lane & 15;
  const int pblk = blockIdx.x >> (NS == 8 ? 3 : 2);
  const int split = blockIdx.x & (NS - 1);
  const int pbase = pblk << 4;
  const int b = pbase >> 8;
  const int p = pbase + kq;
  const int pb = p & 255;
  const int rowbase = ((pb >> 4) << 10) + ((pb & 15) << 3);
  const size_t xb = (size_t)b * NTOK * 64;

  f32x4 acc = (f32x4){0.f, 0.f, 0.f, 0.f};
  const int c0 = split * (128 / NS);
#pragma unroll 4
  for (int c32 = c0; c32 < c0 + 128 / NS; ++c32) {
    int t = c32 >> 1;
    int hc = (c32 & 1) << 5;
    int token = rowbase + ((t >> 3) << 7) + (t & 7);
    const float* xp = x + xb + ((size_t)token << 6) + hc + (g << 3);
    bf16x8 a = cvt8(*(const f32x4*)xp, *(const f32x4*)(xp + 4));
    bf16x8 wb = *(const bf16x8*)(W2T + ((nt * 16 + kq) << 12) + (c32 << 5) + (g << 3));
    acc = MFMA(a, wb, acc);
  }
#pragma unroll
  for (int r = 0; r < 4; ++r) {
    int prow = pbase + g * 4 + r;
    convP[((split << 11) + prow) * 64 + nt * 16 + kq] = acc[r];
  }
}

// ---------------- bias + LayerNorm + kv projection (16 rows/block) --------
template <int NS>
__global__ __launch_bounds__(256) void kv_k(const float* __restrict__ convP,
                                            const float* __restrict__ b_sr,
                                            const float* __restrict__ ln_g,
                                            const float* __restrict__ ln_b,
                                            const float* __restrict__ w_kv,
                                            short* __restrict__ Kw,
                                            short* __restrict__ Vtw) {
  __shared__ float wT[64 * 128];  // [c][d] swizzled: d ^ (c&31)
  __shared__ float rowz[16][64];
  const int tid = threadIdx.x;
#pragma unroll 8
  for (int i = 0; i < 32; ++i) {
    int idx = i * 256 + tid;
    int d2 = idx >> 6, c = idx & 63;
    wT[(c << 7) + (d2 ^ (c & 31))] = w_kv[idx];
  }
  const int gr0 = blockIdx.x << 4;
  {
    const int c = tid & 63;
    const int w = tid >> 6;
#pragma unroll
    for (int pass = 0; pass < 4; ++pass) {
      int row = pass * 4 + w;
      int gr = gr0 + row;
      float y = b_sr[c];
#pragma unroll
      for (int s = 0; s < NS; ++s) y += convP[((s << 11) + gr) * 64 + c];
      float s1 = y, s2 = y * y;
#pragma unroll
      for (int off = 1; off < 64; off <<= 1) {
        s1 += __shfl_xor(s1, off);
        s2 += __shfl_xor(s2, off);
      }
      float mu = s1 * 0.015625f;
      float var = s2 * 0.015625f - mu * mu;
      float rs = rsqrtf(var + 1e-5f);
      rowz[row][c] = (y - mu) * rs * ln_g[c] + ln_b[c];
    }
  }
  __syncthreads();
  {
    const int d = tid & 127;
    const int rg = tid >> 7;
#pragma unroll
    for (int rr = 0; rr < 8; ++rr) {
      int row = rg * 8 + rr;
      float acc = 0.f;
#pragma unroll
      for (int c = 0; c < 64; ++c) acc += rowz[row][c] * wT[(c << 7) + (d ^ (c & 31))];
      int gr = gr0 + row;
      int bb = gr >> 8, m = gr & 255;
      if (d < 64)
        Kw[((bb << 8) + m) * 64 + d] = f2bf(acc);
      else
        Vtw[((bb << 6) + (d - 64)) * 256 + m] = f2bf(acc);
    }
  }
}

// ---------------- fold projections into KV --------------------------------
__global__ __launch_bounds__(256) void kq_k(const short* __restrict__ Kw,
                                            const short* __restrict__ Vtw,
                                            const float* __restrict__ w_q,
                                            const float* __restrict__ w_proj,
                                            short* __restrict__ KQ,
                                            short* __restrict__ VPT) {
  __shared__ float wl[4096];
  const int t = threadIdx.x;
  const bool isV = blockIdx.x >= 32;
  const float* wsrc = isV ? w_proj : w_q;
  const float scale = isV ? 1.0f : 0.125f;
#pragma unroll
  for (int i = 0; i < 16; ++i) wl[i * 256 + t] = wsrc[i * 256 + t] * scale;
  __syncthreads();

  if (!isV) {
    int b = blockIdx.x >> 2, kg = blockIdx.x & 3;
    int key = kg * 64 + (t >> 2), cc = (t & 3) * 16;
    const short* krow = Kw + (((b << 8) + key) << 6);
    bf16x8 kr[8];
#pragma unroll
    for (int i = 0; i < 8; ++i) kr[i] = *(const bf16x8*)(krow + i * 8);
    float acc[16];
#pragma unroll
    for (int c = 0; c < 16; ++c) acc[c] = 0.f;
#pragma unroll
    for (int o = 0; o < 64; ++o) {
      float kv = bf2f(kr[o >> 3][o & 7]);
#pragma unroll
      for (int c = 0; c < 16; ++c) acc[c] += kv * wl[o * 64 + cc + c];
    }
    short* dst = KQ + (((b << 8) + key) << 6) + cc;
#pragma unroll
    for (int c = 0; c < 16; ++c) dst[c] = f2bf(acc[c]);
  } else {
    int blk = blockIdx.x - 32;
    int b = blk >> 2, og = blk & 3;
    int o = og * 16 + (t >> 4), kc = (t & 15) * 16;
    const short* vt = Vtw + ((size_t)b << 14);
    float acc[16];
#pragma unroll
    for (int j = 0; j < 16; ++j) acc[j] = 0.f;
#pragma unroll
    for (int d = 0; d < 64; ++d) {
      float wv = wl[o * 64 + d];
      const short* vr = vt + d * 256 + kc;
      bf16x8 v0 = *(const bf16x8*)(vr);
      bf16x8 v1 = *(const bf16x8*)(vr + 8);
#pragma unroll
      for (int j = 0; j < 8; ++j) acc[j] += wv * bf2f(v0[j]);
#pragma unroll
      for (int j = 0; j < 8; ++j) acc[8 + j] += wv * bf2f(v1[j]);
    }
    short* dst = VPT + ((size_t)b << 14) + o * 256 + kc;
#pragma unroll
    for (int j = 0; j < 16; ++j) dst[j] = f2bf(acc[j]);
  }
}

// ---------------- attention v4.1: S^T = KQ*x^T, lane-local E, P*VP --------
__global__ __launch_bounds__(512, 2) void attn_k(
    const float* __restrict__ x, const short* __restrict__ KQ,
    const short* __restrict__ VPT, const float* __restrict__ bproj,
    float* __restrict__ out) {
  __shared__ short KQl[256 * 64];   // rows 128B, 16B-slot ^= (row&7)
  __shared__ short VPTl[64 * 264];  // rows padded to 528B, 8B-slot ^= (o&7)

  const int tid = threadIdx.x;
  const int lane = tid & 63;
  const int wid = tid >> 6;
  const int b = blockIdx.x >> 6;
  const int n0 = (blockIdx.x & 63) << 8;
  const int g = lane >> 4;
  const int kq = lane & 15;
  const int tok0 = n0 + wid * 32;
  const size_t xbase = ((size_t)b * NTOK + tok0) * 64;

  // ---- x / bias loads issued first (hide HBM latency under staging) ----
  bf16x8 xa[2][2];
#pragma unroll
  for (int m = 0; m < 2; ++m)
#pragma unroll
    for (int kc = 0; kc < 2; ++kc) {
      const float* p = x + xbase + (size_t)(m * 16 + kq) * 64 + kc * 32 + g * 8;
      xa[m][kc] = cvt8(*(const f32x4*)p, *(const f32x4*)(p + 4));
    }
  float bp[4];
#pragma unroll
  for (int nd = 0; nd < 4; ++nd) bp[nd] = bproj[nd * 16 + kq];

  // ---- stage KQ and VPT (coalesced reads, swizzled writes) ----
  {
    const uint4* Kg = (const uint4*)(KQ + ((size_t)b << 14));
#pragma unroll
    for (int i = 0; i < 4; ++i) {
      int id = i * 512 + tid;
      int row = id >> 3, s = id & 7;
      *(uint4*)(&KQl[(row << 6) + ((s ^ (row & 7)) << 3)]) = Kg[id];
    }
    const uint4* Vg = (const uint4*)(VPT + ((size_t)b << 14));
#pragma unroll
    for (int i = 0; i < 4; ++i) {
      int id = i * 512 + tid;
      int o = id >> 5, s = id & 31;
      uint4 v = Vg[id];
      int p0 = (2 * s) ^ (o & 7);
      int p1 = (2 * s + 1) ^ (o & 7);
      uint2 lo; lo.x = v.x; lo.y = v.y;
      uint2 hi; hi.x = v.z; hi.y = v.w;
      *(uint2*)(&VPTl[o * 264 + p0 * 4]) = lo;
      *(uint2*)(&VPTl[o * 264 + p1 * 4]) = hi;
    }
  }
  __syncthreads();

  f32x4 pv[2][4];
#pragma unroll
  for (int m = 0; m < 2; ++m)
#pragma unroll
    for (int nd = 0; nd < 4; ++nd) pv[m][nd] = (f32x4){0.f, 0.f, 0.f, 0.f};
  float rsum[2] = {0.f, 0.f};
  f32x4 epair[2][2];  // [m][kt&1]

  __builtin_amdgcn_s_setprio(1);
#pragma unroll
  for (int kt = 0; kt < 16; ++kt) {
    int key = kt * 16 + kq;
    bf16x8 kb0 = *(const bf16x8*)(&KQl[(key << 6) + (((0 * 4 + g) ^ (key & 7)) << 3)]);
    bf16x8 kb1 = *(const bf16x8*)(&KQl[(key << 6) + (((1 * 4 + g) ^ (key & 7)) << 3)]);
#pragma unroll
    for (int m = 0; m < 2; ++m) {
      f32x4 s4 = MFMA(kb0, xa[m][0], ((f32x4){0.f, 0.f, 0.f, 0.f}));
      s4 = MFMA(kb1, xa[m][1], s4);
      f32x4 e4;
#pragma unroll
      for (int r = 0; r < 4; ++r) e4[r] = __expf(s4[r]);
      rsum[m] += e4[0] + e4[1] + e4[2] + e4[3];
      epair[m][kt & 1] = e4;
    }
    if (kt & 1) {
      int c = kt >> 1;
      bf16x8 a8[2];
#pragma unroll
      for (int m = 0; m < 2; ++m) {
        a8[m][0] = f2bf(epair[m][0][0]); a8[m][1] = f2bf(epair[m][0][1]);
        a8[m][2] = f2bf(epair[m][0][2]); a8[m][3] = f2bf(epair[m][0][3]);
        a8[m][4] = f2bf(epair[m][1][0]); a8[m][5] = f2bf(epair[m][1][1]);
        a8[m][6] = f2bf(epair[m][1][2]); a8[m][7] = f2bf(epair[m][1][3]);
      }
#pragma unroll
      for (int nd = 0; nd < 4; ++nd) {
        int o = nd * 16 + kq;
        const short* vrow = &VPTl[o * 264];
        int pa = (8 * c + g) ^ (o & 7);
        int pb_ = (8 * c + g + 4) ^ (o & 7);
        bf16x4 lo = *(const bf16x4*)(vrow + pa * 4);
        bf16x4 hi = *(const bf16x4*)(vrow + pb_ * 4);
        bf16x8 vb = (bf16x8){lo[0], lo[1], lo[2], lo[3], hi[0], hi[1], hi[2], hi[3]};
#pragma unroll
        for (int m = 0; m < 2; ++m) pv[m][nd] = MFMA(a8[m], vb, pv[m][nd]);
      }
    }
  }
  __builtin_amdgcn_s_setprio(0);

  float rinv[2];
#pragma unroll
  for (int m = 0; m < 2; ++m) {
    float s = rsum[m];
    s += __shfl_xor(s, 16);
    s += __shfl_xor(s, 32);
    rinv[m] = 1.0f / s;
  }

#pragma unroll
  for (int m = 0; m < 2; ++m)
#pragma unroll
    for (int r = 0; r < 4; ++r) {
      float iv = __shfl(rinv[m], g * 4 + r);
      size_t rowoff = xbase + (size_t)(m * 16 + g * 4 + r) * 64;
#pragma unroll
      for (int nd = 0; nd < 4; ++nd)
        out[rowoff + nd * 16 + kq] = pv[m][nd][r] * iv + bp[nd];
    }
}

extern "C" void kernel_launch(void* const* d_in, const int* in_sizes, int n_in,
                              void* d_out, int out_size, void* d_ws, size_t ws_size,
                              hipStream_t stream) {
  const float* x = (const float*)d_in[0];
  const float* w_q = (const float*)d_in[3];
  const float* w_kv = (const float*)d_in[4];
  const float* w_sr = (const float*)d_in[5];
  const float* b_sr = (const float*)d_in[6];
  const float* ln_g = (const float*)d_in[7];
  const float* ln_b = (const float*)d_in[8];
  const float* w_proj = (const float*)d_in[9];
  const float* b_proj = (const float*)d_in[10];
  float* out = (float*)d_out;

  char* ws = (char*)d_ws;
  short* W2T = (short*)(ws);           // 512KB [dead after conv_k]
  short* KQ = (short*)(ws);            // 256KB [aliases W2T]
  short* VPT = (short*)(ws + 262144);  // 256KB [aliases W2T]
  float* convP = (float*)(ws + 524288);

  hipLaunchKernelGGL(prep_k, dim3(64), dim3(256), 0, stream, w_sr, W2T);

  short *Kw, *Vtw;
  // split-8 needs convP=4MB -> ws end 5,242,880; fall back to proven split-4
  // layout (end 3,145,728) if the workspace is smaller. ws_size is constant
  // across calls, so this branch is deterministic.
  if (ws_size >= 5242880) {
    Kw = (short*)(ws + 4718592);
    Vtw = (short*)(ws + 4980736);
    hipLaunchKernelGGL(conv_k<8>, dim3(1024), dim3(256), 0, stream, x, W2T, convP);
    hipLaunchKernelGGL(kv_k<8>, dim3(128), dim3(256), 0, stream, convP, b_sr,
                       ln_g, ln_b, w_kv, Kw, Vtw);
  } else {
    Kw = (short*)(ws + 2621440);
    Vtw = (short*)(ws + 2883584);
    hipLaunchKernelGGL(conv_k<4>, dim3(512), dim3(256), 0, stream, x, W2T, convP);
    hipLaunchKernelGGL(kv_k<4>, dim3(128), dim3(256), 0, stream, convP, b_sr,
                       ln_g, ln_b, w_kv, Kw, Vtw);
  }
  hipLaunchKernelGGL(kq_k, dim3(64), dim3(256), 0, stream, Kw, Vtw, w_q, w_proj,
                     KQ, VPT);
  hipLaunchKernelGGL(attn_k, dim3(512), dim3(512), 0, stream, x, KQ, VPT,
                     b_proj, out);
}

// Round 13
// 60.785 us; speedup vs baseline: 1.4270x; 1.2124x over previous
//
#include <hip/hip_runtime.h>
#include <hip/hip_bf16.h>

#define BATCH 8
#define NTOK 16384

typedef __attribute__((ext_vector_type(8))) short bf16x8;
typedef __attribute__((ext_vector_type(4))) short bf16x4;
typedef __attribute__((ext_vector_type(4))) float f32x4;
typedef __attribute__((ext_vector_type(4))) unsigned int u32x4;

#define MFMA(a, b, c) __builtin_amdgcn_mfma_f32_16x16x32_bf16(a, b, c, 0, 0, 0)

// proven path: RNE f32->bf16 via bit ops
__device__ __forceinline__ short f2bf(float f) {
  unsigned u = __builtin_bit_cast(unsigned, f);
  u = (u + 0x7fffu + ((u >> 16) & 1u)) >> 16;  // RNE
  return (short)u;
}
__device__ __forceinline__ float bf2f(short s) {
  unsigned u = ((unsigned)(unsigned short)s) << 16;
  return __builtin_bit_cast(float, u);
}
__device__ __forceinline__ bf16x8 cvt8(f32x4 v0, f32x4 v1) {
  bf16x8 a;
  a[0] = f2bf(v0[0]); a[1] = f2bf(v0[1]); a[2] = f2bf(v0[2]); a[3] = f2bf(v0[3]);
  a[4] = f2bf(v1[0]); a[5] = f2bf(v1[1]); a[6] = f2bf(v1[2]); a[7] = f2bf(v1[3]);
  return a;
}
// HW packed conversion via HIP header (compiler-lowered, NOT hand asm).
// memcpy instead of bit_cast: __hip_bfloat162 is not trivially copyable.
__device__ __forceinline__ unsigned pk2(float a, float b) {
  __hip_bfloat162 h = __float22bfloat162_rn(float2{a, b});
  unsigned r;
  __builtin_memcpy(&r, &h, 4);
  return r;
}
__device__ __forceinline__ bf16x8 cvt8pk(f32x4 v0, f32x4 v1) {
  u32x4 w;
  w[0] = pk2(v0[0], v0[1]);
  w[1] = pk2(v0[2], v0[3]);
  w[2] = pk2(v1[0], v1[1]);
  w[3] = pk2(v1[2], v1[3]);
  return __builtin_bit_cast(bf16x8, w);
}

// ---------------- prep: conv weight transpose via padded LDS tile ---------
__global__ __launch_bounds__(256) void prep_k(const float* __restrict__ w_sr,
                                              short* __restrict__ W2T) {
  __shared__ float tile[64 * 65];
  const int o = blockIdx.x;  // 64 blocks
  const float* src = w_sr + (o << 12);
  short* dst = W2T + (o << 12);
  const int tid = threadIdx.x;
#pragma unroll
  for (int k = 0; k < 16; ++k) {
    int idx = k * 256 + tid;
    int c = idx >> 6, t = idx & 63;
    tile[c * 65 + t] = src[idx];
  }
  __syncthreads();
#pragma unroll
  for (int k = 0; k < 16; ++k) {
    int idx = k * 256 + tid;
    int t = idx >> 6, c = idx & 63;
    dst[idx] = f2bf(tile[c * 65 + t]);
  }
}

// ---------------- conv v2: LDS-staged coalesced x, MFMA GEMM, K-split 4 ---
// Block = (b, pi, split). Stages image rows y0=pi*8+2*split, y0+1 as bf16
// into swizzled LDS (slot^=(col>>3)&7), then 32 MFMA iters read ds_read_b128.
// Same K-ranges and RNE bits as the proven gather version -> convP bitwise eq.
__global__ __launch_bounds__(256, 4) void conv_k(const float* __restrict__ x,
                                                 const short* __restrict__ W2T,
                                                 float* __restrict__ convP) {
  __shared__ short Axl[2 * 128 * 64];  // 32KB: [ti][col][c]
  const int tid = threadIdx.x;
  const int lane = tid & 63;
  const int nt = tid >> 6;
  const int g = lane >> 4;
  const int kq = lane & 15;          // pj
  const int pblk = blockIdx.x >> 2;  // b*16 + pi
  const int split = blockIdx.x & 3;
  const int pbase = pblk << 4;
  const int b = pbase >> 8;
  const int pi = pblk & 15;
  const size_t xb = (size_t)b * NTOK * 64;
  const int y0 = pi * 8 + split * 2;

  // stage: 2048 16B-chunks; thread t does chunks {i*256+t}
#pragma unroll
  for (int i = 0; i < 8; ++i) {
    int cid = i * 256 + tid;
    int row = cid >> 3;               // ti*128 + col
    int ti = row >> 7, col = row & 127;
    int slot = (cid & 7) ^ ((col >> 3) & 7);
    const float* src = x + xb + ((size_t)((y0 + ti) * 128 + col) << 6) + ((cid & 7) << 3);
    bf16x8 v = cvt8(*(const f32x4*)src, *(const f32x4*)(src + 4));
    *(bf16x8*)(&Axl[(row << 6) + (slot << 3)]) = v;
  }
  __syncthreads();

  f32x4 acc = (f32x4){0.f, 0.f, 0.f, 0.f};
  const int c0 = split << 5;
#pragma unroll 4
  for (int c32 = c0; c32 < c0 + 32; ++c32) {
    int t = c32 >> 1;
    int ti = (t >> 3) & 1;            // t>>3 = 2*split + ti
    int tj = t & 7;
    int row = ti * 128 + kq * 8 + tj;
    int slot = (((c32 & 1) << 2) + g) ^ (kq & 7);
    bf16x8 a = *(const bf16x8*)(&Axl[(row << 6) + (slot << 3)]);
    bf16x8 wb = *(const bf16x8*)(W2T + ((nt * 16 + kq) << 12) + (c32 << 5) + (g << 3));
    acc = MFMA(a, wb, acc);
  }
#pragma unroll
  for (int r = 0; r < 4; ++r) {
    int prow = pbase + g * 4 + r;
    convP[((split << 11) + prow) * 64 + nt * 16 + kq] = acc[r];
  }
}

// ---------------- bias + LayerNorm + kv projection (16 rows/block) --------
__global__ __launch_bounds__(256) void kv_k(const float* __restrict__ convP,
                                            const float* __restrict__ b_sr,
                                            const float* __restrict__ ln_g,
                                            const float* __restrict__ ln_b,
                                            const float* __restrict__ w_kv,
                                            short* __restrict__ Kw,
                                            short* __restrict__ Vtw) {
  __shared__ float wT[64 * 128];  // [c][d] swizzled: d ^ (c&31)
  __shared__ float rowz[16][64];
  const int tid = threadIdx.x;
#pragma unroll 8
  for (int i = 0; i < 32; ++i) {
    int idx = i * 256 + tid;
    int d2 = idx >> 6, c = idx & 63;
    wT[(c << 7) + (d2 ^ (c & 31))] = w_kv[idx];
  }
  const int gr0 = blockIdx.x << 4;
  {
    const int c = tid & 63;
    const int w = tid >> 6;
#pragma unroll
    for (int pass = 0; pass < 4; ++pass) {
      int row = pass * 4 + w;
      int gr = gr0 + row;
      float y = b_sr[c];
#pragma unroll
      for (int s = 0; s < 4; ++s) y += convP[((s << 11) + gr) * 64 + c];
      float s1 = y, s2 = y * y;
#pragma unroll
      for (int off = 1; off < 64; off <<= 1) {
        s1 += __shfl_xor(s1, off);
        s2 += __shfl_xor(s2, off);
      }
      float mu = s1 * 0.015625f;
      float var = s2 * 0.015625f - mu * mu;
      float rs = rsqrtf(var + 1e-5f);
      rowz[row][c] = (y - mu) * rs * ln_g[c] + ln_b[c];
    }
  }
  __syncthreads();
  {
    const int d = tid & 127;
    const int rg = tid >> 7;
#pragma unroll
    for (int rr = 0; rr < 8; ++rr) {
      int row = rg * 8 + rr;
      float acc = 0.f;
#pragma unroll
      for (int c = 0; c < 64; ++c) acc += rowz[row][c] * wT[(c << 7) + (d ^ (c & 31))];
      int gr = gr0 + row;
      int bb = gr >> 8, m = gr & 255;
      if (d < 64)
        Kw[((bb << 8) + m) * 64 + d] = f2bf(acc);
      else
        Vtw[((bb << 6) + (d - 64)) * 256 + m] = f2bf(acc);
    }
  }
}

// ---------------- fold projections into KV --------------------------------
__global__ __launch_bounds__(256) void kq_k(const short* __restrict__ Kw,
                                            const short* __restrict__ Vtw,
                                            const float* __restrict__ w_q,
                                            const float* __restrict__ w_proj,
                                            short* __restrict__ KQ,
                                            short* __restrict__ VPT) {
  __shared__ float wl[4096];
  const int t = threadIdx.x;
  const bool isV = blockIdx.x >= 32;
  const float* wsrc = isV ? w_proj : w_q;
  const float scale = isV ? 1.0f : 0.125f;
#pragma unroll
  for (int i = 0; i < 16; ++i) wl[i * 256 + t] = wsrc[i * 256 + t] * scale;
  __syncthreads();

  if (!isV) {
    int b = blockIdx.x >> 2, kg = blockIdx.x & 3;
    int key = kg * 64 + (t >> 2), cc = (t & 3) * 16;
    const short* krow = Kw + (((b << 8) + key) << 6);
    bf16x8 kr[8];
#pragma unroll
    for (int i = 0; i < 8; ++i) kr[i] = *(const bf16x8*)(krow + i * 8);
    float acc[16];
#pragma unroll
    for (int c = 0; c < 16; ++c) acc[c] = 0.f;
#pragma unroll
    for (int o = 0; o < 64; ++o) {
      float kv = bf2f(kr[o >> 3][o & 7]);
#pragma unroll
      for (int c = 0; c < 16; ++c) acc[c] += kv * wl[o * 64 + cc + c];
    }
    short* dst = KQ + (((b << 8) + key) << 6) + cc;
#pragma unroll
    for (int c = 0; c < 16; ++c) dst[c] = f2bf(acc[c]);
  } else {
    int blk = blockIdx.x - 32;
    int b = blk >> 2, og = blk & 3;
    int o = og * 16 + (t >> 4), kc = (t & 15) * 16;
    const short* vt = Vtw + ((size_t)b << 14);
    float acc[16];
#pragma unroll
    for (int j = 0; j < 16; ++j) acc[j] = 0.f;
#pragma unroll
    for (int d = 0; d < 64; ++d) {
      float wv = wl[o * 64 + d];
      const short* vr = vt + d * 256 + kc;
      bf16x8 v0 = *(const bf16x8*)(vr);
      bf16x8 v1 = *(const bf16x8*)(vr + 8);
#pragma unroll
      for (int j = 0; j < 8; ++j) acc[j] += wv * bf2f(v0[j]);
#pragma unroll
      for (int j = 0; j < 8; ++j) acc[8 + j] += wv * bf2f(v1[j]);
    }
    short* dst = VPT + ((size_t)b << 14) + o * 256 + kc;
#pragma unroll
    for (int j = 0; j < 16; ++j) dst[j] = f2bf(acc[j]);
  }
}

// ---------------- attention v4.2: S^T = KQ*x^T, lane-local E, P*VP --------
__global__ __launch_bounds__(512, 2) void attn_k(
    const float* __restrict__ x, const short* __restrict__ KQ,
    const short* __restrict__ VPT, const float* __restrict__ bproj,
    float* __restrict__ out) {
  __shared__ short KQl[256 * 64];   // rows 128B, 16B-slot ^= (row&7)
  __shared__ short VPTl[64 * 264];  // rows padded to 528B, 8B-slot ^= (o&7)

  const int tid = threadIdx.x;
  const int lane = tid & 63;
  const int wid = tid >> 6;
  const int b = blockIdx.x >> 6;
  const int n0 = (blockIdx.x & 63) << 8;
  const int g = lane >> 4;
  const int kq = lane & 15;
  const int tok0 = n0 + wid * 32;
  const size_t xbase = ((size_t)b * NTOK + tok0) * 64;

  // ---- x / bias loads issued first (hide HBM latency under staging) ----
  bf16x8 xa[2][2];
#pragma unroll
  for (int m = 0; m < 2; ++m)
#pragma unroll
    for (int kc = 0; kc < 2; ++kc) {
      const float* p = x + xbase + (size_t)(m * 16 + kq) * 64 + kc * 32 + g * 8;
      xa[m][kc] = cvt8pk(*(const f32x4*)p, *(const f32x4*)(p + 4));
    }
  float bp[4];
#pragma unroll
  for (int nd = 0; nd < 4; ++nd) bp[nd] = bproj[nd * 16 + kq];

  // ---- stage KQ and VPT (coalesced reads, swizzled writes) ----
  {
    const uint4* Kg = (const uint4*)(KQ + ((size_t)b << 14));
#pragma unroll
    for (int i = 0; i < 4; ++i) {
      int id = i * 512 + tid;
      int row = id >> 3, s = id & 7;
      *(uint4*)(&KQl[(row << 6) + ((s ^ (row & 7)) << 3)]) = Kg[id];
    }
    const uint4* Vg = (const uint4*)(VPT + ((size_t)b << 14));
#pragma unroll
    for (int i = 0; i < 4; ++i) {
      int id = i * 512 + tid;
      int o = id >> 5, s = id & 31;
      uint4 v = Vg[id];
      int p0 = (2 * s) ^ (o & 7);
      int p1 = (2 * s + 1) ^ (o & 7);
      uint2 lo; lo.x = v.x; lo.y = v.y;
      uint2 hi; hi.x = v.z; hi.y = v.w;
      *(uint2*)(&VPTl[o * 264 + p0 * 4]) = lo;
      *(uint2*)(&VPTl[o * 264 + p1 * 4]) = hi;
    }
  }
  __syncthreads();

  f32x4 pv[2][4];
#pragma unroll
  for (int m = 0; m < 2; ++m)
#pragma unroll
    for (int nd = 0; nd < 4; ++nd) pv[m][nd] = (f32x4){0.f, 0.f, 0.f, 0.f};
  float rsum[2] = {0.f, 0.f};
  f32x4 epair[2][2];  // [m][kt&1]

  __builtin_amdgcn_s_setprio(1);
#pragma unroll
  for (int kt = 0; kt < 16; ++kt) {
    int key = kt * 16 + kq;
    bf16x8 kb0 = *(const bf16x8*)(&KQl[(key << 6) + (((0 * 4 + g) ^ (key & 7)) << 3)]);
    bf16x8 kb1 = *(const bf16x8*)(&KQl[(key << 6) + (((1 * 4 + g) ^ (key & 7)) << 3)]);
#pragma unroll
    for (int m = 0; m < 2; ++m) {
      f32x4 s4 = MFMA(kb0, xa[m][0], ((f32x4){0.f, 0.f, 0.f, 0.f}));
      s4 = MFMA(kb1, xa[m][1], s4);
      f32x4 e4;
#pragma unroll
      for (int r = 0; r < 4; ++r) e4[r] = __expf(s4[r]);
      rsum[m] += e4[0] + e4[1] + e4[2] + e4[3];
      epair[m][kt & 1] = e4;
    }
    if (kt & 1) {
      int c = kt >> 1;
      bf16x8 a8[2];
#pragma unroll
      for (int m = 0; m < 2; ++m) {
        u32x4 w;
        w[0] = pk2(epair[m][0][0], epair[m][0][1]);
        w[1] = pk2(epair[m][0][2], epair[m][0][3]);
        w[2] = pk2(epair[m][1][0], epair[m][1][1]);
        w[3] = pk2(epair[m][1][2], epair[m][1][3]);
        a8[m] = __builtin_bit_cast(bf16x8, w);
      }
#pragma unroll
      for (int nd = 0; nd < 4; ++nd) {
        int o = nd * 16 + kq;
        const short* vrow = &VPTl[o * 264];
        int pa = (8 * c + g) ^ (o & 7);
        int pb_ = (8 * c + g + 4) ^ (o & 7);
        bf16x4 lo = *(const bf16x4*)(vrow + pa * 4);
        bf16x4 hi = *(const bf16x4*)(vrow + pb_ * 4);
        bf16x8 vb = (bf16x8){lo[0], lo[1], lo[2], lo[3], hi[0], hi[1], hi[2], hi[3]};
#pragma unroll
        for (int m = 0; m < 2; ++m) pv[m][nd] = MFMA(a8[m], vb, pv[m][nd]);
      }
    }
  }
  __builtin_amdgcn_s_setprio(0);

  float rinv[2];
#pragma unroll
  for (int m = 0; m < 2; ++m) {
    float s = rsum[m];
    s += __shfl_xor(s, 16);
    s += __shfl_xor(s, 32);
    rinv[m] = 1.0f / s;
  }

#pragma unroll
  for (int m = 0; m < 2; ++m)
#pragma unroll
    for (int r = 0; r < 4; ++r) {
      float iv = __shfl(rinv[m], g * 4 + r);
      size_t rowoff = xbase + (size_t)(m * 16 + g * 4 + r) * 64;
#pragma unroll
      for (int nd = 0; nd < 4; ++nd)
        out[rowoff + nd * 16 + kq] = pv[m][nd][r] * iv + bp[nd];
    }
}

extern "C" void kernel_launch(void* const* d_in, const int* in_sizes, int n_in,
                              void* d_out, int out_size, void* d_ws, size_t ws_size,
                              hipStream_t stream) {
  const float* x = (const float*)d_in[0];
  const float* w_q = (const float*)d_in[3];
  const float* w_kv = (const float*)d_in[4];
  const float* w_sr = (const float*)d_in[5];
  const float* b_sr = (const float*)d_in[6];
  const float* ln_g = (const float*)d_in[7];
  const float* ln_b = (const float*)d_in[8];
  const float* w_proj = (const float*)d_in[9];
  const float* b_proj = (const float*)d_in[10];
  float* out = (float*)d_out;

  // fixed, proven layout (3,145,728 B); KQ/VPT alias W2T (dead after conv_k)
  char* ws = (char*)d_ws;
  short* W2T = (short*)(ws);
  short* KQ = (short*)(ws);
  short* VPT = (short*)(ws + 262144);
  float* convP = (float*)(ws + 524288);
  short* Kw = (short*)(ws + 2621440);
  short* Vtw = (short*)(ws + 2883584);

  hipLaunchKernelGGL(prep_k, dim3(64), dim3(256), 0, stream, w_sr, W2T);
  hipLaunchKernelGGL(conv_k, dim3(512), dim3(256), 0, stream, x, W2T, convP);
  hipLaunchKernelGGL(kv_k, dim3(128), dim3(256), 0, stream, convP, b_sr, ln_g,
                     ln_b, w_kv, Kw, Vtw);
  hipLaunchKernelGGL(kq_k, dim3(64), dim3(256), 0, stream, Kw, Vtw, w_q, w_proj,
                     KQ, VPT);
  hipLaunchKernelGGL(attn_k, dim3(512), dim3(512), 0, stream, x, KQ, VPT,
                     b_proj, out);
}

// Round 14
// 53.452 us; speedup vs baseline: 1.6227x; 1.1372x over previous
//
#include <hip/hip_runtime.h>
#include <hip/hip_bf16.h>

#define BATCH 8
#define NTOK 16384

typedef __attribute__((ext_vector_type(8))) short bf16x8;
typedef __attribute__((ext_vector_type(4))) short bf16x4;
typedef __attribute__((ext_vector_type(4))) float f32x4;
typedef __attribute__((ext_vector_type(4))) unsigned int u32x4;

#define MFMA(a, b, c) __builtin_amdgcn_mfma_f32_16x16x32_bf16(a, b, c, 0, 0, 0)

// proven path: RNE f32->bf16 via bit ops
__device__ __forceinline__ short f2bf(float f) {
  unsigned u = __builtin_bit_cast(unsigned, f);
  u = (u + 0x7fffu + ((u >> 16) & 1u)) >> 16;  // RNE
  return (short)u;
}
__device__ __forceinline__ bf16x8 cvt8(f32x4 v0, f32x4 v1) {
  bf16x8 a;
  a[0] = f2bf(v0[0]); a[1] = f2bf(v0[1]); a[2] = f2bf(v0[2]); a[3] = f2bf(v0[3]);
  a[4] = f2bf(v1[0]); a[5] = f2bf(v1[1]); a[6] = f2bf(v1[2]); a[7] = f2bf(v1[3]);
  return a;
}
// HW packed conversion via HIP header (compiler-lowered, NOT hand asm)
__device__ __forceinline__ unsigned pk2(float a, float b) {
  __hip_bfloat162 h = __float22bfloat162_rn(float2{a, b});
  unsigned r;
  __builtin_memcpy(&r, &h, 4);
  return r;
}
__device__ __forceinline__ bf16x8 cvt8pk(f32x4 v0, f32x4 v1) {
  u32x4 w;
  w[0] = pk2(v0[0], v0[1]);
  w[1] = pk2(v0[2], v0[3]);
  w[2] = pk2(v1[0], v1[1]);
  w[3] = pk2(v1[2], v1[3]);
  return __builtin_bit_cast(bf16x8, w);
}

// ---------------- prep: conv weight transpose via padded LDS tile ---------
__global__ __launch_bounds__(256) void prep_k(const float* __restrict__ w_sr,
                                              short* __restrict__ W2T) {
  __shared__ float tile[64 * 65];
  const int o = blockIdx.x;  // 64 blocks
  const float* src = w_sr + (o << 12);
  short* dst = W2T + (o << 12);
  const int tid = threadIdx.x;
#pragma unroll
  for (int k = 0; k < 16; ++k) {
    int idx = k * 256 + tid;
    int c = idx >> 6, t = idx & 63;
    tile[c * 65 + t] = src[idx];
  }
  __syncthreads();
#pragma unroll
  for (int k = 0; k < 16; ++k) {
    int idx = k * 256 + tid;
    int t = idx >> 6, c = idx & 63;
    dst[idx] = f2bf(tile[c * 65 + t]);
  }
}

// ---------------- conv v2: LDS-staged coalesced x, MFMA GEMM, K-split 4 ---
__global__ __launch_bounds__(256, 4) void conv_k(const float* __restrict__ x,
                                                 const short* __restrict__ W2T,
                                                 float* __restrict__ convP) {
  __shared__ short Axl[2 * 128 * 64];  // 32KB: [ti][col][c]
  const int tid = threadIdx.x;
  const int lane = tid & 63;
  const int nt = tid >> 6;
  const int g = lane >> 4;
  const int kq = lane & 15;          // pj
  const int pblk = blockIdx.x >> 2;  // b*16 + pi
  const int split = blockIdx.x & 3;
  const int pbase = pblk << 4;
  const int b = pbase >> 8;
  const int pi = pblk & 15;
  const size_t xb = (size_t)b * NTOK * 64;
  const int y0 = pi * 8 + split * 2;

#pragma unroll
  for (int i = 0; i < 8; ++i) {
    int cid = i * 256 + tid;
    int row = cid >> 3;               // ti*128 + col
    int ti = row >> 7, col = row & 127;
    int slot = (cid & 7) ^ ((col >> 3) & 7);
    const float* src = x + xb + ((size_t)((y0 + ti) * 128 + col) << 6) + ((cid & 7) << 3);
    bf16x8 v = cvt8(*(const f32x4*)src, *(const f32x4*)(src + 4));
    *(bf16x8*)(&Axl[(row << 6) + (slot << 3)]) = v;
  }
  __syncthreads();

  f32x4 acc = (f32x4){0.f, 0.f, 0.f, 0.f};
  const int c0 = split << 5;
#pragma unroll 4
  for (int c32 = c0; c32 < c0 + 32; ++c32) {
    int t = c32 >> 1;
    int ti = (t >> 3) & 1;
    int tj = t & 7;
    int row = ti * 128 + kq * 8 + tj;
    int slot = (((c32 & 1) << 2) + g) ^ (kq & 7);
    bf16x8 a = *(const bf16x8*)(&Axl[(row << 6) + (slot << 3)]);
    bf16x8 wb = *(const bf16x8*)(W2T + ((nt * 16 + kq) << 12) + (c32 << 5) + (g << 3));
    acc = MFMA(a, wb, acc);
  }
#pragma unroll
  for (int r = 0; r < 4; ++r) {
    int prow = pbase + g * 4 + r;
    convP[((split << 11) + prow) * 64 + nt * 16 + kq] = acc[r];
  }
}

// ---------------- fused: bias + LN + kv-proj + folded q/out projections ---
// 128 blocks x 16 rows. LN -> K,V (f32, LDS) -> KQ = K*(SCALE*w_q),
// VPT = w_proj*V^T, written bf16. Skips the Kw/Vtw global roundtrip.
__global__ __launch_bounds__(256) void kvkq_k(
    const float* __restrict__ convP, const float* __restrict__ b_sr,
    const float* __restrict__ ln_g, const float* __restrict__ ln_b,
    const float* __restrict__ w_kv, const float* __restrict__ w_q,
    const float* __restrict__ w_proj, short* __restrict__ KQ,
    short* __restrict__ VPT) {
  __shared__ float wT[64 * 128];   // w_kv [c][d ^ (c&31)]
  __shared__ float wq[64 * 64];    // SCALE*w_q [o][cc]
  __shared__ float wp[64 * 64];    // w_proj [o][d]
  __shared__ float rowz[16][64];
  __shared__ float Kf[16][68];     // padded (stride 68 -> 2-way max)
  __shared__ float Vf[16][68];
  const int tid = threadIdx.x;
#pragma unroll 8
  for (int i = 0; i < 32; ++i) {
    int idx = i * 256 + tid;
    int d2 = idx >> 6, c = idx & 63;
    wT[(c << 7) + (d2 ^ (c & 31))] = w_kv[idx];
  }
#pragma unroll
  for (int i = 0; i < 16; ++i) {
    int idx = i * 256 + tid;
    wq[idx] = w_q[idx] * 0.125f;
    wp[idx] = w_proj[idx];
  }
  const int gr0 = blockIdx.x << 4;
  const int b = gr0 >> 8;
  const int key0 = gr0 & 255;
  {
    const int c = tid & 63;
    const int w = tid >> 6;
#pragma unroll
    for (int pass = 0; pass < 4; ++pass) {
      int row = pass * 4 + w;
      int gr = gr0 + row;
      float y = b_sr[c];
#pragma unroll
      for (int s = 0; s < 4; ++s) y += convP[((s << 11) + gr) * 64 + c];
      float s1 = y, s2 = y * y;
#pragma unroll
      for (int off = 1; off < 64; off <<= 1) {
        s1 += __shfl_xor(s1, off);
        s2 += __shfl_xor(s2, off);
      }
      float mu = s1 * 0.015625f;
      float var = s2 * 0.015625f - mu * mu;
      float rs = rsqrtf(var + 1e-5f);
      rowz[row][c] = (y - mu) * rs * ln_g[c] + ln_b[c];
    }
  }
  __syncthreads();
  // K,V: row = tid>>4, 8 cols each
  {
    const int row = tid >> 4;
    const int c8 = (tid & 15) * 8;  // 0..120; K cols c8<64, V cols c8-64 else
    float acc[8];
#pragma unroll
    for (int j = 0; j < 8; ++j) acc[j] = 0.f;
#pragma unroll
    for (int c = 0; c < 64; ++c) {
      float rz = rowz[row][c];
#pragma unroll
      for (int j = 0; j < 8; ++j) acc[j] += rz * wT[(c << 7) + ((c8 + j) ^ (c & 31))];
    }
    if (c8 < 64) {
#pragma unroll
      for (int j = 0; j < 8; ++j) Kf[row][c8 + j] = acc[j];
    } else {
#pragma unroll
      for (int j = 0; j < 8; ++j) Vf[row][c8 - 64 + j] = acc[j];
    }
  }
  __syncthreads();
  // KQ: row = tid>>4, 4 cols
  {
    const int row = tid >> 4;
    const int cc4 = (tid & 15) * 4;
    float a[4] = {0.f, 0.f, 0.f, 0.f};
#pragma unroll
    for (int o = 0; o < 64; ++o) {
      float kv = Kf[row][o];
#pragma unroll
      for (int j = 0; j < 4; ++j) a[j] += kv * wq[o * 64 + cc4 + j];
    }
    short* dst = KQ + (size_t)(gr0 + row) * 64 + cc4;
#pragma unroll
    for (int j = 0; j < 4; ++j) dst[j] = f2bf(a[j]);
  }
  // VPT: o = tid>>2, 4 keys
  {
    const int o = tid >> 2;
    const int k4 = (tid & 3) * 4;
    float v[4] = {0.f, 0.f, 0.f, 0.f};
#pragma unroll
    for (int d = 0; d < 64; ++d) {
      float wv = wp[o * 64 + d];
#pragma unroll
      for (int j = 0; j < 4; ++j) v[j] += wv * Vf[k4 + j][d];
    }
    short* dst = VPT + ((size_t)b << 14) + o * 256 + key0 + k4;
#pragma unroll
    for (int j = 0; j < 4; ++j) dst[j] = f2bf(v[j]);
  }
}

// ---------------- attention v5: 2-stage pipelined chunks ------------------
// QK(c+1) issued before exp/pack/PV(c): MFMA pipe overlaps VALU exp/pack.
__global__ __launch_bounds__(512, 2) void attn_k(
    const float* __restrict__ x, const short* __restrict__ KQ,
    const short* __restrict__ VPT, const float* __restrict__ bproj,
    float* __restrict__ out) {
  __shared__ short KQl[256 * 64];   // rows 128B, 16B-slot ^= (row&7)
  __shared__ short VPTl[64 * 264];  // rows padded 528B, 8B-slot ^= (o&7)

  const int tid = threadIdx.x;
  const int lane = tid & 63;
  const int wid = tid >> 6;
  const int b = blockIdx.x >> 6;
  const int n0 = (blockIdx.x & 63) << 8;
  const int g = lane >> 4;
  const int kq = lane & 15;
  const int tok0 = n0 + wid * 32;
  const size_t xbase = ((size_t)b * NTOK + tok0) * 64;

  bf16x8 xa[2][2];
#pragma unroll
  for (int m = 0; m < 2; ++m)
#pragma unroll
    for (int kc = 0; kc < 2; ++kc) {
      const float* p = x + xbase + (size_t)(m * 16 + kq) * 64 + kc * 32 + g * 8;
      xa[m][kc] = cvt8pk(*(const f32x4*)p, *(const f32x4*)(p + 4));
    }
  float bp[4];
#pragma unroll
  for (int nd = 0; nd < 4; ++nd) bp[nd] = bproj[nd * 16 + kq];

  {
    const uint4* Kg = (const uint4*)(KQ + ((size_t)b << 14));
#pragma unroll
    for (int i = 0; i < 4; ++i) {
      int id = i * 512 + tid;
      int row = id >> 3, s = id & 7;
      *(uint4*)(&KQl[(row << 6) + ((s ^ (row & 7)) << 3)]) = Kg[id];
    }
    const uint4* Vg = (const uint4*)(VPT + ((size_t)b << 14));
#pragma unroll
    for (int i = 0; i < 4; ++i) {
      int id = i * 512 + tid;
      int o = id >> 5, s = id & 31;
      uint4 v = Vg[id];
      int p0 = (2 * s) ^ (o & 7);
      int p1 = (2 * s + 1) ^ (o & 7);
      uint2 lo; lo.x = v.x; lo.y = v.y;
      uint2 hi; hi.x = v.z; hi.y = v.w;
      *(uint2*)(&VPTl[o * 264 + p0 * 4]) = lo;
      *(uint2*)(&VPTl[o * 264 + p1 * 4]) = hi;
    }
  }
  __syncthreads();

  f32x4 pv[2][4];
#pragma unroll
  for (int m = 0; m < 2; ++m)
#pragma unroll
    for (int nd = 0; nd < 4; ++nd) pv[m][nd] = (f32x4){0.f, 0.f, 0.f, 0.f};
  float rsum[2] = {0.f, 0.f};

  auto qkchunk = [&](int C, f32x4 (&S)[2][2]) {
#pragma unroll
    for (int kk = 0; kk < 2; ++kk) {
      int key = (2 * C + kk) * 16 + kq;
      bf16x8 kb0 = *(const bf16x8*)(&KQl[(key << 6) + (((0 + g) ^ (key & 7)) << 3)]);
      bf16x8 kb1 = *(const bf16x8*)(&KQl[(key << 6) + (((4 + g) ^ (key & 7)) << 3)]);
#pragma unroll
      for (int m = 0; m < 2; ++m) {
        f32x4 s4 = MFMA(kb0, xa[m][0], ((f32x4){0.f, 0.f, 0.f, 0.f}));
        S[m][kk] = MFMA(kb1, xa[m][1], s4);
      }
    }
  };

  f32x4 scur[2][2], snxt[2][2];
  qkchunk(0, scur);

  __builtin_amdgcn_s_setprio(1);
#pragma unroll
  for (int c = 0; c < 8; ++c) {
    if (c < 7) qkchunk(c + 1, snxt);  // overlaps the VALU below (MFMA pipe)
    bf16x8 a8[2];
#pragma unroll
    for (int m = 0; m < 2; ++m) {
      f32x4 e0, e1;
#pragma unroll
      for (int r = 0; r < 4; ++r) e0[r] = __expf(scur[m][0][r]);
#pragma unroll
      for (int r = 0; r < 4; ++r) e1[r] = __expf(scur[m][1][r]);
      rsum[m] += e0[0] + e0[1] + e0[2] + e0[3] + e1[0] + e1[1] + e1[2] + e1[3];
      u32x4 w;
      w[0] = pk2(e0[0], e0[1]);
      w[1] = pk2(e0[2], e0[3]);
      w[2] = pk2(e1[0], e1[1]);
      w[3] = pk2(e1[2], e1[3]);
      a8[m] = __builtin_bit_cast(bf16x8, w);
    }
#pragma unroll
    for (int nd = 0; nd < 4; ++nd) {
      int o = nd * 16 + kq;
      const short* vrow = &VPTl[o * 264];
      int pa = (8 * c + g) ^ (o & 7);
      int pb_ = (8 * c + g + 4) ^ (o & 7);
      bf16x4 lo = *(const bf16x4*)(vrow + pa * 4);
      bf16x4 hi = *(const bf16x4*)(vrow + pb_ * 4);
      bf16x8 vb = (bf16x8){lo[0], lo[1], lo[2], lo[3], hi[0], hi[1], hi[2], hi[3]};
#pragma unroll
      for (int m = 0; m < 2; ++m) pv[m][nd] = MFMA(a8[m], vb, pv[m][nd]);
    }
#pragma unroll
    for (int m = 0; m < 2; ++m) {
      scur[m][0] = snxt[m][0];
      scur[m][1] = snxt[m][1];
    }
  }
  __builtin_amdgcn_s_setprio(0);

  float rinv[2];
#pragma unroll
  for (int m = 0; m < 2; ++m) {
    float s = rsum[m];
    s += __shfl_xor(s, 16);
    s += __shfl_xor(s, 32);
    rinv[m] = 1.0f / s;
  }

#pragma unroll
  for (int m = 0; m < 2; ++m)
#pragma unroll
    for (int r = 0; r < 4; ++r) {
      float iv = __shfl(rinv[m], g * 4 + r);
      size_t rowoff = xbase + (size_t)(m * 16 + g * 4 + r) * 64;
#pragma unroll
      for (int nd = 0; nd < 4; ++nd)
        out[rowoff + nd * 16 + kq] = pv[m][nd][r] * iv + bp[nd];
    }
}

extern "C" void kernel_launch(void* const* d_in, const int* in_sizes, int n_in,
                              void* d_out, int out_size, void* d_ws, size_t ws_size,
                              hipStream_t stream) {
  const float* x = (const float*)d_in[0];
  const float* w_q = (const float*)d_in[3];
  const float* w_kv = (const float*)d_in[4];
  const float* w_sr = (const float*)d_in[5];
  const float* b_sr = (const float*)d_in[6];
  const float* ln_g = (const float*)d_in[7];
  const float* ln_b = (const float*)d_in[8];
  const float* w_proj = (const float*)d_in[9];
  const float* b_proj = (const float*)d_in[10];
  float* out = (float*)d_out;

  // workspace 2,621,440 B; KQ/VPT alias W2T (dead after conv_k)
  char* ws = (char*)d_ws;
  short* W2T = (short*)(ws);
  short* KQ = (short*)(ws);
  short* VPT = (short*)(ws + 262144);
  float* convP = (float*)(ws + 524288);

  hipLaunchKernelGGL(prep_k, dim3(64), dim3(256), 0, stream, w_sr, W2T);
  hipLaunchKernelGGL(conv_k, dim3(512), dim3(256), 0, stream, x, W2T, convP);
  hipLaunchKernelGGL(kvkq_k, dim3(128), dim3(256), 0, stream, convP, b_sr, ln_g,
                     ln_b, w_kv, w_q, w_proj, KQ, VPT);
  hipLaunchKernelGGL(attn_k, dim3(512), dim3(512), 0, stream, x, KQ, VPT,
                     b_proj, out);
}

// Round 16
// 51.761 us; speedup vs baseline: 1.6758x; 1.0327x over previous
//
#include <hip/hip_runtime.h>
#include <hip/hip_bf16.h>

#define BATCH 8
#define NTOK 16384

typedef __attribute__((ext_vector_type(8))) short bf16x8;
typedef __attribute__((ext_vector_type(4))) short bf16x4;
typedef __attribute__((ext_vector_type(4))) float f32x4;
typedef __attribute__((ext_vector_type(4))) unsigned int u32x4;

#define MFMA(a, b, c) __builtin_amdgcn_mfma_f32_16x16x32_bf16(a, b, c, 0, 0, 0)

// proven path: RNE f32->bf16 via bit ops
__device__ __forceinline__ short f2bf(float f) {
  unsigned u = __builtin_bit_cast(unsigned, f);
  u = (u + 0x7fffu + ((u >> 16) & 1u)) >> 16;  // RNE
  return (short)u;
}
__device__ __forceinline__ bf16x8 cvt8(f32x4 v0, f32x4 v1) {
  bf16x8 a;
  a[0] = f2bf(v0[0]); a[1] = f2bf(v0[1]); a[2] = f2bf(v0[2]); a[3] = f2bf(v0[3]);
  a[4] = f2bf(v1[0]); a[5] = f2bf(v1[1]); a[6] = f2bf(v1[2]); a[7] = f2bf(v1[3]);
  return a;
}
// HW packed conversion via HIP header (compiler-lowered, NOT hand asm)
__device__ __forceinline__ unsigned pk2(float a, float b) {
  __hip_bfloat162 h = __float22bfloat162_rn(float2{a, b});
  unsigned r;
  __builtin_memcpy(&r, &h, 4);
  return r;
}
__device__ __forceinline__ bf16x8 cvt8pk(f32x4 v0, f32x4 v1) {
  u32x4 w;
  w[0] = pk2(v0[0], v0[1]);
  w[1] = pk2(v0[2], v0[3]);
  w[2] = pk2(v1[0], v1[1]);
  w[3] = pk2(v1[2], v1[3]);
  return __builtin_bit_cast(bf16x8, w);
}

// ---------------- prep: conv weight transpose via padded LDS tile ---------
__global__ __launch_bounds__(256) void prep_k(const float* __restrict__ w_sr,
                                              short* __restrict__ W2T) {
  __shared__ float tile[64 * 65];
  const int o = blockIdx.x;  // 64 blocks
  const float* src = w_sr + (o << 12);
  short* dst = W2T + (o << 12);
  const int tid = threadIdx.x;
#pragma unroll
  for (int k = 0; k < 16; ++k) {
    int idx = k * 256 + tid;
    int c = idx >> 6, t = idx & 63;
    tile[c * 65 + t] = src[idx];
  }
  __syncthreads();
#pragma unroll
  for (int k = 0; k < 16; ++k) {
    int idx = k * 256 + tid;
    int t = idx >> 6, c = idx & 63;
    dst[idx] = f2bf(tile[c * 65 + t]);
  }
}

// ---------------- conv v2: LDS-staged coalesced x, MFMA GEMM, K-split 4 ---
__global__ __launch_bounds__(256, 4) void conv_k(const float* __restrict__ x,
                                                 const short* __restrict__ W2T,
                                                 float* __restrict__ convP) {
  __shared__ short Axl[2 * 128 * 64];  // 32KB: [ti][col][c]
  const int tid = threadIdx.x;
  const int lane = tid & 63;
  const int nt = tid >> 6;
  const int g = lane >> 4;
  const int kq = lane & 15;          // pj
  const int pblk = blockIdx.x >> 2;  // b*16 + pi
  const int split = blockIdx.x & 3;
  const int pbase = pblk << 4;
  const int b = pbase >> 8;
  const int pi = pblk & 15;
  const size_t xb = (size_t)b * NTOK * 64;
  const int y0 = pi * 8 + split * 2;

#pragma unroll
  for (int i = 0; i < 8; ++i) {
    int cid = i * 256 + tid;
    int row = cid >> 3;               // ti*128 + col
    int ti = row >> 7, col = row & 127;
    int slot = (cid & 7) ^ ((col >> 3) & 7);
    const float* src = x + xb + ((size_t)((y0 + ti) * 128 + col) << 6) + ((cid & 7) << 3);
    bf16x8 v = cvt8(*(const f32x4*)src, *(const f32x4*)(src + 4));
    *(bf16x8*)(&Axl[(row << 6) + (slot << 3)]) = v;
  }
  __syncthreads();

  f32x4 acc = (f32x4){0.f, 0.f, 0.f, 0.f};
  const int c0 = split << 5;
#pragma unroll 4
  for (int c32 = c0; c32 < c0 + 32; ++c32) {
    int t = c32 >> 1;
    int ti = (t >> 3) & 1;
    int tj = t & 7;
    int row = ti * 128 + kq * 8 + tj;
    int slot = (((c32 & 1) << 2) + g) ^ (kq & 7);
    bf16x8 a = *(const bf16x8*)(&Axl[(row << 6) + (slot << 3)]);
    bf16x8 wb = *(const bf16x8*)(W2T + ((nt * 16 + kq) << 12) + (c32 << 5) + (g << 3));
    acc = MFMA(a, wb, acc);
  }
#pragma unroll
  for (int r = 0; r < 4; ++r) {
    int prow = pbase + g * 4 + r;
    convP[((split << 11) + prow) * 64 + nt * 16 + kq] = acc[r];
  }
}

// ---------------- fused: bias + LN + kv-proj + folded q/out projections ---
__global__ __launch_bounds__(256) void kvkq_k(
    const float* __restrict__ convP, const float* __restrict__ b_sr,
    const float* __restrict__ ln_g, const float* __restrict__ ln_b,
    const float* __restrict__ w_kv, const float* __restrict__ w_q,
    const float* __restrict__ w_proj, short* __restrict__ KQ,
    short* __restrict__ VPT) {
  __shared__ float wT[64 * 128];   // w_kv [c][d ^ (c&31)]
  __shared__ float wq[64 * 64];    // SCALE*w_q [o][cc]
  __shared__ float wp[64 * 64];    // w_proj [o][d]
  __shared__ float rowz[16][64];
  __shared__ float Kf[16][68];
  __shared__ float Vf[16][68];
  const int tid = threadIdx.x;
#pragma unroll 8
  for (int i = 0; i < 32; ++i) {
    int idx = i * 256 + tid;
    int d2 = idx >> 6, c = idx & 63;
    wT[(c << 7) + (d2 ^ (c & 31))] = w_kv[idx];
  }
#pragma unroll
  for (int i = 0; i < 16; ++i) {
    int idx = i * 256 + tid;
    wq[idx] = w_q[idx] * 0.125f;
    wp[idx] = w_proj[idx];
  }
  const int gr0 = blockIdx.x << 4;
  const int b = gr0 >> 8;
  const int key0 = gr0 & 255;
  {
    const int c = tid & 63;
    const int w = tid >> 6;
#pragma unroll
    for (int pass = 0; pass < 4; ++pass) {
      int row = pass * 4 + w;
      int gr = gr0 + row;
      float y = b_sr[c];
#pragma unroll
      for (int s = 0; s < 4; ++s) y += convP[((s << 11) + gr) * 64 + c];
      float s1 = y, s2 = y * y;
#pragma unroll
      for (int off = 1; off < 64; off <<= 1) {
        s1 += __shfl_xor(s1, off);
        s2 += __shfl_xor(s2, off);
      }
      float mu = s1 * 0.015625f;
      float var = s2 * 0.015625f - mu * mu;
      float rs = rsqrtf(var + 1e-5f);
      rowz[row][c] = (y - mu) * rs * ln_g[c] + ln_b[c];
    }
  }
  __syncthreads();
  {
    const int row = tid >> 4;
    const int c8 = (tid & 15) * 8;
    float acc[8];
#pragma unroll
    for (int j = 0; j < 8; ++j) acc[j] = 0.f;
#pragma unroll
    for (int c = 0; c < 64; ++c) {
      float rz = rowz[row][c];
#pragma unroll
      for (int j = 0; j < 8; ++j) acc[j] += rz * wT[(c << 7) + ((c8 + j) ^ (c & 31))];
    }
    if (c8 < 64) {
#pragma unroll
      for (int j = 0; j < 8; ++j) Kf[row][c8 + j] = acc[j];
    } else {
#pragma unroll
      for (int j = 0; j < 8; ++j) Vf[row][c8 - 64 + j] = acc[j];
    }
  }
  __syncthreads();
  {
    const int row = tid >> 4;
    const int cc4 = (tid & 15) * 4;
    float a[4] = {0.f, 0.f, 0.f, 0.f};
#pragma unroll
    for (int o = 0; o < 64; ++o) {
      float kv = Kf[row][o];
#pragma unroll
      for (int j = 0; j < 4; ++j) a[j] += kv * wq[o * 64 + cc4 + j];
    }
    short* dst = KQ + (size_t)(gr0 + row) * 64 + cc4;
#pragma unroll
    for (int j = 0; j < 4; ++j) dst[j] = f2bf(a[j]);
  }
  {
    const int o = tid >> 2;
    const int k4 = (tid & 3) * 4;
    float v[4] = {0.f, 0.f, 0.f, 0.f};
#pragma unroll
    for (int d = 0; d < 64; ++d) {
      float wv = wp[o * 64 + d];
#pragma unroll
      for (int j = 0; j < 4; ++j) v[j] += wv * Vf[k4 + j][d];
    }
    short* dst = VPT + ((size_t)b << 14) + o * 256 + key0 + k4;
#pragma unroll
    for (int j = 0; j < 4; ++j) dst[j] = f2bf(v[j]);
  }
}

// ---------------- attention v6: 3-stage pipeline + rowsum-via-MFMA --------
// QK(c+1) || exp/pack(c) || PV(c-1). Softmax denominator computed by an
// all-ones B-fragment MFMA -> same C-layout as pv -> zero shuffles.
__global__ __launch_bounds__(512, 2) void attn_k(
    const float* __restrict__ x, const short* __restrict__ KQ,
    const short* __restrict__ VPT, const float* __restrict__ bproj,
    float* __restrict__ out) {
  __shared__ short KQl[256 * 64];   // rows 128B, 16B-slot ^= (row&7)
  __shared__ short VPTl[64 * 264];  // rows padded 528B, 8B-slot ^= (o&7)

  const int tid = threadIdx.x;
  const int lane = tid & 63;
  const int wid = tid >> 6;
  const int b = blockIdx.x >> 6;
  const int n0 = (blockIdx.x & 63) << 8;
  const int g = lane >> 4;
  const int kq = lane & 15;
  const int tok0 = n0 + wid * 32;
  const size_t xbase = ((size_t)b * NTOK + tok0) * 64;

  bf16x8 xa[2][2];
#pragma unroll
  for (int m = 0; m < 2; ++m)
#pragma unroll
    for (int kc = 0; kc < 2; ++kc) {
      const float* p = x + xbase + (size_t)(m * 16 + kq) * 64 + kc * 32 + g * 8;
      xa[m][kc] = cvt8pk(*(const f32x4*)p, *(const f32x4*)(p + 4));
    }
  float bp[4];
#pragma unroll
  for (int nd = 0; nd < 4; ++nd) bp[nd] = bproj[nd * 16 + kq];

  {
    const uint4* Kg = (const uint4*)(KQ + ((size_t)b << 14));
#pragma unroll
    for (int i = 0; i < 4; ++i) {
      int id = i * 512 + tid;
      int row = id >> 3, s = id & 7;
      *(uint4*)(&KQl[(row << 6) + ((s ^ (row & 7)) << 3)]) = Kg[id];
    }
    const uint4* Vg = (const uint4*)(VPT + ((size_t)b << 14));
#pragma unroll
    for (int i = 0; i < 4; ++i) {
      int id = i * 512 + tid;
      int o = id >> 5, s = id & 31;
      uint4 v = Vg[id];
      int p0 = (2 * s) ^ (o & 7);
      int p1 = (2 * s + 1) ^ (o & 7);
      uint2 lo; lo.x = v.x; lo.y = v.y;
      uint2 hi; hi.x = v.z; hi.y = v.w;
      *(uint2*)(&VPTl[o * 264 + p0 * 4]) = lo;
      *(uint2*)(&VPTl[o * 264 + p1 * 4]) = hi;
    }
  }
  __syncthreads();

  f32x4 pv[2][4];
  f32x4 pvs[2];  // rowsum accumulators (ones-MFMA)
#pragma unroll
  for (int m = 0; m < 2; ++m) {
#pragma unroll
    for (int nd = 0; nd < 4; ++nd) pv[m][nd] = (f32x4){0.f, 0.f, 0.f, 0.f};
    pvs[m] = (f32x4){0.f, 0.f, 0.f, 0.f};
  }
  const short one_bf = (short)0x3F80;  // bf16 1.0
  const bf16x8 ones8 = (bf16x8){one_bf, one_bf, one_bf, one_bf,
                                one_bf, one_bf, one_bf, one_bf};

  auto qkchunk = [&](int C, f32x4 (&S)[2][2]) {
#pragma unroll
    for (int kk = 0; kk < 2; ++kk) {
      int key = (2 * C + kk) * 16 + kq;
      bf16x8 kb0 = *(const bf16x8*)(&KQl[(key << 6) + (((0 + g) ^ (key & 7)) << 3)]);
      bf16x8 kb1 = *(const bf16x8*)(&KQl[(key << 6) + (((4 + g) ^ (key & 7)) << 3)]);
#pragma unroll
      for (int m = 0; m < 2; ++m) {
        f32x4 s4 = MFMA(kb0, xa[m][0], ((f32x4){0.f, 0.f, 0.f, 0.f}));
        S[m][kk] = MFMA(kb1, xa[m][1], s4);
      }
    }
  };
  auto pvgroup = [&](int C, bf16x8 (&a8)[2]) {
#pragma unroll
    for (int nd = 0; nd < 4; ++nd) {
      int o = nd * 16 + kq;
      const short* vrow = &VPTl[o * 264];
      int pa = (8 * C + g) ^ (o & 7);
      int pb_ = (8 * C + g + 4) ^ (o & 7);
      bf16x4 lo = *(const bf16x4*)(vrow + pa * 4);
      bf16x4 hi = *(const bf16x4*)(vrow + pb_ * 4);
      bf16x8 vb = (bf16x8){lo[0], lo[1], lo[2], lo[3], hi[0], hi[1], hi[2], hi[3]};
#pragma unroll
      for (int m = 0; m < 2; ++m) pv[m][nd] = MFMA(a8[m], vb, pv[m][nd]);
    }
#pragma unroll
    for (int m = 0; m < 2; ++m) pvs[m] = MFMA(a8[m], ones8, pvs[m]);
  };

  f32x4 scur[2][2], snxt[2][2];
  bf16x8 a8prev[2];
  qkchunk(0, scur);

  __builtin_amdgcn_s_setprio(1);
#pragma unroll
  for (int c = 0; c < 8; ++c) {
    if (c < 7) qkchunk(c + 1, snxt);
    bf16x8 a8cur[2];
#pragma unroll
    for (int m = 0; m < 2; ++m) {
      f32x4 e0, e1;
#pragma unroll
      for (int r = 0; r < 4; ++r) e0[r] = __expf(scur[m][0][r]);
#pragma unroll
      for (int r = 0; r < 4; ++r) e1[r] = __expf(scur[m][1][r]);
      u32x4 w;
      w[0] = pk2(e0[0], e0[1]);
      w[1] = pk2(e0[2], e0[3]);
      w[2] = pk2(e1[0], e1[1]);
      w[3] = pk2(e1[2], e1[3]);
      a8cur[m] = __builtin_bit_cast(bf16x8, w);
    }
    if (c > 0) pvgroup(c - 1, a8prev);
    a8prev[0] = a8cur[0];
    a8prev[1] = a8cur[1];
#pragma unroll
    for (int m = 0; m < 2; ++m) {
      scur[m][0] = snxt[m][0];
      scur[m][1] = snxt[m][1];
    }
  }
  pvgroup(7, a8prev);
  __builtin_amdgcn_s_setprio(0);

  // normalize + store: rinv is lane-local (pvs shares pv's C-layout)
#pragma unroll
  for (int m = 0; m < 2; ++m)
#pragma unroll
    for (int r = 0; r < 4; ++r) {
      float iv = 1.0f / pvs[m][r];
      size_t rowoff = xbase + (size_t)(m * 16 + g * 4 + r) * 64;
#pragma unroll
      for (int nd = 0; nd < 4; ++nd)
        out[rowoff + nd * 16 + kq] = pv[m][nd][r] * iv + bp[nd];
    }
}

extern "C" void kernel_launch(void* const* d_in, const int* in_sizes, int n_in,
                              void* d_out, int out_size, void* d_ws, size_t ws_size,
                              hipStream_t stream) {
  const float* x = (const float*)d_in[0];
  const float* w_q = (const float*)d_in[3];
  const float* w_kv = (const float*)d_in[4];
  const float* w_sr = (const float*)d_in[5];
  const float* b_sr = (const float*)d_in[6];
  const float* ln_g = (const float*)d_in[7];
  const float* ln_b = (const float*)d_in[8];
  const float* w_proj = (const float*)d_in[9];
  const float* b_proj = (const float*)d_in[10];
  float* out = (float*)d_out;

  // workspace 2,621,440 B; KQ/VPT alias W2T (dead after conv_k)
  char* ws = (char*)d_ws;
  short* W2T = (short*)(ws);
  short* KQ = (short*)(ws);
  short* VPT = (short*)(ws + 262144);
  float* convP = (float*)(ws + 524288);

  hipLaunchKernelGGL(prep_k, dim3(64), dim3(256), 0, stream, w_sr, W2T);
  hipLaunchKernelGGL(conv_k, dim3(512), dim3(256), 0, stream, x, W2T, convP);
  hipLaunchKernelGGL(kvkq_k, dim3(128), dim3(256), 0, stream, convP, b_sr, ln_g,
                     ln_b, w_kv, w_q, w_proj, KQ, VPT);
  hipLaunchKernelGGL(attn_k, dim3(512), dim3(512), 0, stream, x, KQ, VPT,
                     b_proj, out);
}

// Round 17
// 49.424 us; speedup vs baseline: 1.7550x; 1.0473x over previous
//
#include <hip/hip_runtime.h>
#include <hip/hip_bf16.h>

#define BATCH 8
#define NTOK 16384

typedef __attribute__((ext_vector_type(8))) short bf16x8;
typedef __attribute__((ext_vector_type(4))) short bf16x4;
typedef __attribute__((ext_vector_type(4))) float f32x4;
typedef __attribute__((ext_vector_type(4))) unsigned int u32x4;

#define MFMA(a, b, c) __builtin_amdgcn_mfma_f32_16x16x32_bf16(a, b, c, 0, 0, 0)

// proven path: RNE f32->bf16 via bit ops
__device__ __forceinline__ short f2bf(float f) {
  unsigned u = __builtin_bit_cast(unsigned, f);
  u = (u + 0x7fffu + ((u >> 16) & 1u)) >> 16;  // RNE
  return (short)u;
}
__device__ __forceinline__ bf16x8 cvt8(f32x4 v0, f32x4 v1) {
  bf16x8 a;
  a[0] = f2bf(v0[0]); a[1] = f2bf(v0[1]); a[2] = f2bf(v0[2]); a[3] = f2bf(v0[3]);
  a[4] = f2bf(v1[0]); a[5] = f2bf(v1[1]); a[6] = f2bf(v1[2]); a[7] = f2bf(v1[3]);
  return a;
}
// HW packed conversion via HIP header (compiler-lowered, NOT hand asm)
__device__ __forceinline__ unsigned pk2(float a, float b) {
  __hip_bfloat162 h = __float22bfloat162_rn(float2{a, b});
  unsigned r;
  __builtin_memcpy(&r, &h, 4);
  return r;
}
__device__ __forceinline__ bf16x8 cvt8pk(f32x4 v0, f32x4 v1) {
  u32x4 w;
  w[0] = pk2(v0[0], v0[1]);
  w[1] = pk2(v0[2], v0[3]);
  w[2] = pk2(v1[0], v1[1]);
  w[3] = pk2(v1[2], v1[3]);
  return __builtin_bit_cast(bf16x8, w);
}

// ---------------- prep: conv weight transpose via padded LDS tile ---------
__global__ __launch_bounds__(256) void prep_k(const float* __restrict__ w_sr,
                                              short* __restrict__ W2T) {
  __shared__ float tile[64 * 65];
  const int o = blockIdx.x;  // 64 blocks
  const float* src = w_sr + (o << 12);
  short* dst = W2T + (o << 12);
  const int tid = threadIdx.x;
#pragma unroll
  for (int k = 0; k < 16; ++k) {
    int idx = k * 256 + tid;
    int c = idx >> 6, t = idx & 63;
    tile[c * 65 + t] = src[idx];
  }
  __syncthreads();
#pragma unroll
  for (int k = 0; k < 16; ++k) {
    int idx = k * 256 + tid;
    int t = idx >> 6, c = idx & 63;
    dst[idx] = f2bf(tile[c * 65 + t]);
  }
}

// ---------------- conv v2: LDS-staged coalesced x, MFMA GEMM, K-split 4 ---
__global__ __launch_bounds__(256, 4) void conv_k(const float* __restrict__ x,
                                                 const short* __restrict__ W2T,
                                                 float* __restrict__ convP) {
  __shared__ short Axl[2 * 128 * 64];  // 32KB: [ti][col][c]
  const int tid = threadIdx.x;
  const int lane = tid & 63;
  const int nt = tid >> 6;
  const int g = lane >> 4;
  const int kq = lane & 15;          // pj
  const int pblk = blockIdx.x >> 2;  // b*16 + pi
  const int split = blockIdx.x & 3;
  const int pbase = pblk << 4;
  const int b = pbase >> 8;
  const int pi = pblk & 15;
  const size_t xb = (size_t)b * NTOK * 64;
  const int y0 = pi * 8 + split * 2;

#pragma unroll
  for (int i = 0; i < 8; ++i) {
    int cid = i * 256 + tid;
    int row = cid >> 3;               // ti*128 + col
    int ti = row >> 7, col = row & 127;
    int slot = (cid & 7) ^ ((col >> 3) & 7);
    const float* src = x + xb + ((size_t)((y0 + ti) * 128 + col) << 6) + ((cid & 7) << 3);
    bf16x8 v = cvt8(*(const f32x4*)src, *(const f32x4*)(src + 4));
    *(bf16x8*)(&Axl[(row << 6) + (slot << 3)]) = v;
  }
  __syncthreads();

  f32x4 acc = (f32x4){0.f, 0.f, 0.f, 0.f};
  const int c0 = split << 5;
#pragma unroll 4
  for (int c32 = c0; c32 < c0 + 32; ++c32) {
    int t = c32 >> 1;
    int ti = (t >> 3) & 1;
    int tj = t & 7;
    int row = ti * 128 + kq * 8 + tj;
    int slot = (((c32 & 1) << 2) + g) ^ (kq & 7);
    bf16x8 a = *(const bf16x8*)(&Axl[(row << 6) + (slot << 3)]);
    bf16x8 wb = *(const bf16x8*)(W2T + ((nt * 16 + kq) << 12) + (c32 << 5) + (g << 3));
    acc = MFMA(a, wb, acc);
  }
#pragma unroll
  for (int r = 0; r < 4; ++r) {
    int prow = pbase + g * 4 + r;
    convP[((split << 11) + prow) * 64 + nt * 16 + kq] = acc[r];
  }
}

// ---------------- fused: bias + LN + kv-proj + folded q/out projections ---
__global__ __launch_bounds__(256) void kvkq_k(
    const float* __restrict__ convP, const float* __restrict__ b_sr,
    const float* __restrict__ ln_g, const float* __restrict__ ln_b,
    const float* __restrict__ w_kv, const float* __restrict__ w_q,
    const float* __restrict__ w_proj, short* __restrict__ KQ,
    short* __restrict__ VPT) {
  __shared__ float wT[64 * 128];   // w_kv [c][d ^ (c&31)]
  __shared__ float wq[64 * 64];    // SCALE*w_q [o][cc]
  __shared__ float wp[64 * 64];    // w_proj [o][d]
  __shared__ float rowz[16][64];
  __shared__ float Kf[16][68];
  __shared__ float Vf[16][68];
  const int tid = threadIdx.x;
#pragma unroll 8
  for (int i = 0; i < 32; ++i) {
    int idx = i * 256 + tid;
    int d2 = idx >> 6, c = idx & 63;
    wT[(c << 7) + (d2 ^ (c & 31))] = w_kv[idx];
  }
#pragma unroll
  for (int i = 0; i < 16; ++i) {
    int idx = i * 256 + tid;
    wq[idx] = w_q[idx] * 0.125f;
    wp[idx] = w_proj[idx];
  }
  const int gr0 = blockIdx.x << 4;
  const int b = gr0 >> 8;
  const int key0 = gr0 & 255;
  {
    const int c = tid & 63;
    const int w = tid >> 6;
#pragma unroll
    for (int pass = 0; pass < 4; ++pass) {
      int row = pass * 4 + w;
      int gr = gr0 + row;
      float y = b_sr[c];
#pragma unroll
      for (int s = 0; s < 4; ++s) y += convP[((s << 11) + gr) * 64 + c];
      float s1 = y, s2 = y * y;
#pragma unroll
      for (int off = 1; off < 64; off <<= 1) {
        s1 += __shfl_xor(s1, off);
        s2 += __shfl_xor(s2, off);
      }
      float mu = s1 * 0.015625f;
      float var = s2 * 0.015625f - mu * mu;
      float rs = rsqrtf(var + 1e-5f);
      rowz[row][c] = (y - mu) * rs * ln_g[c] + ln_b[c];
    }
  }
  __syncthreads();
  {
    const int row = tid >> 4;
    const int c8 = (tid & 15) * 8;
    float acc[8];
#pragma unroll
    for (int j = 0; j < 8; ++j) acc[j] = 0.f;
#pragma unroll
    for (int c = 0; c < 64; ++c) {
      float rz = rowz[row][c];
#pragma unroll
      for (int j = 0; j < 8; ++j) acc[j] += rz * wT[(c << 7) + ((c8 + j) ^ (c & 31))];
    }
    if (c8 < 64) {
#pragma unroll
      for (int j = 0; j < 8; ++j) Kf[row][c8 + j] = acc[j];
    } else {
#pragma unroll
      for (int j = 0; j < 8; ++j) Vf[row][c8 - 64 + j] = acc[j];
    }
  }
  __syncthreads();
  {
    const int row = tid >> 4;
    const int cc4 = (tid & 15) * 4;
    float a[4] = {0.f, 0.f, 0.f, 0.f};
#pragma unroll
    for (int o = 0; o < 64; ++o) {
      float kv = Kf[row][o];
#pragma unroll
      for (int j = 0; j < 4; ++j) a[j] += kv * wq[o * 64 + cc4 + j];
    }
    short* dst = KQ + (size_t)(gr0 + row) * 64 + cc4;
#pragma unroll
    for (int j = 0; j < 4; ++j) dst[j] = f2bf(a[j]);
  }
  {
    const int o = tid >> 2;
    const int k4 = (tid & 3) * 4;
    float v[4] = {0.f, 0.f, 0.f, 0.f};
#pragma unroll
    for (int d = 0; d < 64; ++d) {
      float wv = wp[o * 64 + d];
#pragma unroll
      for (int j = 0; j < 4; ++j) v[j] += wv * Vf[k4 + j][d];
    }
    short* dst = VPT + ((size_t)b << 14) + o * 256 + key0 + k4;
#pragma unroll
    for (int j = 0; j < 4; ++j) dst[j] = f2bf(v[j]);
  }
}

// ---------------- attention v7: 2-stage pipeline + rowsum-via-MFMA --------
// QK(c+1) issued before exp/pack/PV(c). Softmax denominator via all-ones
// B-fragment MFMA (pvs shares pv's C-layout -> zero shuffles). 2-stage keeps
// register pressure under the (512,2)/128-VGPR budget (v6's 3-stage didn't).
__global__ __launch_bounds__(512, 2) void attn_k(
    const float* __restrict__ x, const short* __restrict__ KQ,
    const short* __restrict__ VPT, const float* __restrict__ bproj,
    float* __restrict__ out) {
  __shared__ short KQl[256 * 64];   // rows 128B, 16B-slot ^= (row&7)
  __shared__ short VPTl[64 * 264];  // rows padded 528B, 8B-slot ^= (o&7)

  const int tid = threadIdx.x;
  const int lane = tid & 63;
  const int wid = tid >> 6;
  const int b = blockIdx.x >> 6;
  const int n0 = (blockIdx.x & 63) << 8;
  const int g = lane >> 4;
  const int kq = lane & 15;
  const int tok0 = n0 + wid * 32;
  const size_t xbase = ((size_t)b * NTOK + tok0) * 64;

  bf16x8 xa[2][2];
#pragma unroll
  for (int m = 0; m < 2; ++m)
#pragma unroll
    for (int kc = 0; kc < 2; ++kc) {
      const float* p = x + xbase + (size_t)(m * 16 + kq) * 64 + kc * 32 + g * 8;
      xa[m][kc] = cvt8pk(*(const f32x4*)p, *(const f32x4*)(p + 4));
    }
  float bp[4];
#pragma unroll
  for (int nd = 0; nd < 4; ++nd) bp[nd] = bproj[nd * 16 + kq];

  {
    const uint4* Kg = (const uint4*)(KQ + ((size_t)b << 14));
#pragma unroll
    for (int i = 0; i < 4; ++i) {
      int id = i * 512 + tid;
      int row = id >> 3, s = id & 7;
      *(uint4*)(&KQl[(row << 6) + ((s ^ (row & 7)) << 3)]) = Kg[id];
    }
    const uint4* Vg = (const uint4*)(VPT + ((size_t)b << 14));
#pragma unroll
    for (int i = 0; i < 4; ++i) {
      int id = i * 512 + tid;
      int o = id >> 5, s = id & 31;
      uint4 v = Vg[id];
      int p0 = (2 * s) ^ (o & 7);
      int p1 = (2 * s + 1) ^ (o & 7);
      uint2 lo; lo.x = v.x; lo.y = v.y;
      uint2 hi; hi.x = v.z; hi.y = v.w;
      *(uint2*)(&VPTl[o * 264 + p0 * 4]) = lo;
      *(uint2*)(&VPTl[o * 264 + p1 * 4]) = hi;
    }
  }
  __syncthreads();

  f32x4 pv[2][4];
  f32x4 pvs[2];  // rowsum accumulators (ones-MFMA)
#pragma unroll
  for (int m = 0; m < 2; ++m) {
#pragma unroll
    for (int nd = 0; nd < 4; ++nd) pv[m][nd] = (f32x4){0.f, 0.f, 0.f, 0.f};
    pvs[m] = (f32x4){0.f, 0.f, 0.f, 0.f};
  }
  const short one_bf = (short)0x3F80;  // bf16 1.0
  const bf16x8 ones8 = (bf16x8){one_bf, one_bf, one_bf, one_bf,
                                one_bf, one_bf, one_bf, one_bf};

  auto qkchunk = [&](int C, f32x4 (&S)[2][2]) {
#pragma unroll
    for (int kk = 0; kk < 2; ++kk) {
      int key = (2 * C + kk) * 16 + kq;
      bf16x8 kb0 = *(const bf16x8*)(&KQl[(key << 6) + (((0 + g) ^ (key & 7)) << 3)]);
      bf16x8 kb1 = *(const bf16x8*)(&KQl[(key << 6) + (((4 + g) ^ (key & 7)) << 3)]);
#pragma unroll
      for (int m = 0; m < 2; ++m) {
        f32x4 s4 = MFMA(kb0, xa[m][0], ((f32x4){0.f, 0.f, 0.f, 0.f}));
        S[m][kk] = MFMA(kb1, xa[m][1], s4);
      }
    }
  };

  f32x4 scur[2][2], snxt[2][2];
  qkchunk(0, scur);

  __builtin_amdgcn_s_setprio(1);
#pragma unroll
  for (int c = 0; c < 8; ++c) {
    if (c < 7) qkchunk(c + 1, snxt);  // MFMA pipe overlaps the VALU below
    bf16x8 a8[2];
#pragma unroll
    for (int m = 0; m < 2; ++m) {
      f32x4 e0, e1;
#pragma unroll
      for (int r = 0; r < 4; ++r) e0[r] = __expf(scur[m][0][r]);
#pragma unroll
      for (int r = 0; r < 4; ++r) e1[r] = __expf(scur[m][1][r]);
      u32x4 w;
      w[0] = pk2(e0[0], e0[1]);
      w[1] = pk2(e0[2], e0[3]);
      w[2] = pk2(e1[0], e1[1]);
      w[3] = pk2(e1[2], e1[3]);
      a8[m] = __builtin_bit_cast(bf16x8, w);
    }
#pragma unroll
    for (int nd = 0; nd < 4; ++nd) {
      int o = nd * 16 + kq;
      const short* vrow = &VPTl[o * 264];
      int pa = (8 * c + g) ^ (o & 7);
      int pb_ = (8 * c + g + 4) ^ (o & 7);
      bf16x4 lo = *(const bf16x4*)(vrow + pa * 4);
      bf16x4 hi = *(const bf16x4*)(vrow + pb_ * 4);
      bf16x8 vb = (bf16x8){lo[0], lo[1], lo[2], lo[3], hi[0], hi[1], hi[2], hi[3]};
#pragma unroll
      for (int m = 0; m < 2; ++m) pv[m][nd] = MFMA(a8[m], vb, pv[m][nd]);
    }
#pragma unroll
    for (int m = 0; m < 2; ++m) pvs[m] = MFMA(a8[m], ones8, pvs[m]);
#pragma unroll
    for (int m = 0; m < 2; ++m) {
      scur[m][0] = snxt[m][0];
      scur[m][1] = snxt[m][1];
    }
  }
  __builtin_amdgcn_s_setprio(0);

  // normalize + store: rinv is lane-local (pvs shares pv's C-layout)
#pragma unroll
  for (int m = 0; m < 2; ++m)
#pragma unroll
    for (int r = 0; r < 4; ++r) {
      float iv = 1.0f / pvs[m][r];
      size_t rowoff = xbase + (size_t)(m * 16 + g * 4 + r) * 64;
#pragma unroll
      for (int nd = 0; nd < 4; ++nd)
        out[rowoff + nd * 16 + kq] = pv[m][nd][r] * iv + bp[nd];
    }
}

extern "C" void kernel_launch(void* const* d_in, const int* in_sizes, int n_in,
                              void* d_out, int out_size, void* d_ws, size_t ws_size,
                              hipStream_t stream) {
  const float* x = (const float*)d_in[0];
  const float* w_q = (const float*)d_in[3];
  const float* w_kv = (const float*)d_in[4];
  const float* w_sr = (const float*)d_in[5];
  const float* b_sr = (const float*)d_in[6];
  const float* ln_g = (const float*)d_in[7];
  const float* ln_b = (const float*)d_in[8];
  const float* w_proj = (const float*)d_in[9];
  const float* b_proj = (const float*)d_in[10];
  float* out = (float*)d_out;

  // workspace 2,621,440 B; KQ/VPT alias W2T (dead after conv_k)
  char* ws = (char*)d_ws;
  short* W2T = (short*)(ws);
  short* KQ = (short*)(ws);
  short* VPT = (short*)(ws + 262144);
  float* convP = (float*)(ws + 524288);

  hipLaunchKernelGGL(prep_k, dim3(64), dim3(256), 0, stream, w_sr, W2T);
  hipLaunchKernelGGL(conv_k, dim3(512), dim3(256), 0, stream, x, W2T, convP);
  hipLaunchKernelGGL(kvkq_k, dim3(128), dim3(256), 0, stream, convP, b_sr, ln_g,
                     ln_b, w_kv, w_q, w_proj, KQ, VPT);
  hipLaunchKernelGGL(attn_k, dim3(512), dim3(512), 0, stream, x, KQ, VPT,
                     b_proj, out);
}